// Round 3
// baseline (487.883 us; speedup 1.0000x reference)
//
#include <hip/hip_runtime.h>
#include <hip/hip_bf16.h>

#define L_SEQ 4096
#define NH 8
#define DH 128
#define NQB 32
#define NKB 64
#define TOPK 32

typedef __bf16 bf16x8 __attribute__((ext_vector_type(8)));
typedef float floatx4 __attribute__((ext_vector_type(4)));

static_assert(sizeof(bf16x8) == 16, "bf16x8 must be 16B");

// ---------------- K -> bf16 [h][l][d] ----------------
__global__ __launch_bounds__(256) void k_convert_k(const float* __restrict__ kin,
                                                   __bf16* __restrict__ kb)
{
    int t = blockIdx.x * 256 + threadIdx.x;
    long base = (long)t * 8;                     // flat [l][h][d]
    int d  = (int)(base & 127);
    int lh = (int)(base >> 7);
    int h  = lh & 7;
    int l  = lh >> 3;
    const float4* s = (const float4*)(kin + base);
    float4 a = s[0], b = s[1];
    bf16x8 o;
    o[0] = (__bf16)a.x; o[1] = (__bf16)a.y; o[2] = (__bf16)a.z; o[3] = (__bf16)a.w;
    o[4] = (__bf16)b.x; o[5] = (__bf16)b.y; o[6] = (__bf16)b.z; o[7] = (__bf16)b.w;
    *(bf16x8*)(kb + ((long)(h * L_SEQ + l)) * DH + d) = o;
}

// ---------------- V -> bf16 transposed [h][d][l] ----------------
__global__ __launch_bounds__(256) void k_transpose_v(const float* __restrict__ vin,
                                                     __bf16* __restrict__ vt)
{
    __shared__ float tile[64][129];
    const int lb = blockIdx.x, h = blockIdx.y, t = threadIdx.x;
    {
        const int r = t >> 2, seg = (t & 3) * 32;
        const float* src = vin + ((long)((lb * 64 + r) * NH + h)) * DH + seg;
#pragma unroll
        for (int j = 0; j < 8; ++j) {
            float4 x = ((const float4*)src)[j];
            float* dstp = &tile[r][seg + 4 * j];
            dstp[0] = x.x; dstp[1] = x.y; dstp[2] = x.z; dstp[3] = x.w;
        }
    }
    __syncthreads();
    {
        const int d = t >> 1, lh2 = (t & 1) * 32;
        bf16x8 ov[4];
#pragma unroll
        for (int i = 0; i < 32; ++i) ov[i >> 3][i & 7] = (__bf16)tile[lh2 + i][d];
        bf16x8* dst = (bf16x8*)(vt + ((long)(h * DH + d)) * L_SEQ + lb * 64 + lh2);
#pragma unroll
        for (int j = 0; j < 4; ++j) dst[j] = ov[j];
    }
}

// ---------------- block pooling ----------------
__global__ __launch_bounds__(128) void k_pool(const float* __restrict__ q,
                                              const float* __restrict__ k,
                                              float* __restrict__ pq,
                                              float* __restrict__ pks)
{
    const int y = blockIdx.x, h = blockIdx.y, d = threadIdx.x;
    if (y < NKB) {
        float acc = 0.f;
        const int l0 = y * 64;
        for (int r = 0; r < 64; ++r) acc += k[((long)((l0 + r) * NH + h)) * DH + d];
        pks[((long)(h * NKB + y)) * DH + d] = acc;
    } else {
        const int qb = y - NKB;
        float acc = 0.f;
        const int l0 = qb * 128;
        for (int r = 0; r < 128; ++r) acc += q[((long)((l0 + r) * NH + h)) * DH + d];
        pq[((long)(h * NQB + qb)) * DH + d] = acc;
    }
}

// ---------------- routing: rank-based top-32 ----------------
__global__ __launch_bounds__(64) void k_route(const float* __restrict__ pq,
                                              const float* __restrict__ pks,
                                              int* __restrict__ lut)
{
    __shared__ float qv[128];
    __shared__ float sc[64];
    const int qi = blockIdx.x, h = blockIdx.y, j = threadIdx.x;
    qv[j]      = pq[((long)(h * NQB + qi)) * DH + j];
    qv[j + 64] = pq[((long)(h * NQB + qi)) * DH + j + 64];
    __syncthreads();
    const float* pr = pks + ((long)(h * NKB + j)) * DH;
    float s = 0.f;
    for (int d = 0; d < 128; ++d) s += qv[d] * pr[d];
    sc[j] = s;
    __syncthreads();
    int rank = 0;
    for (int j2 = 0; j2 < 64; ++j2) {
        float o = sc[j2];
        rank += (o > s) || (o == s && j2 < j);
    }
    if (rank < TOPK) lut[(h * NQB + qi) * TOPK + rank] = j;
}

// ---------------- kv: fk=softmax(K-row); kv[h][c][d] += fk^T@V via atomics ----------------
__global__ __launch_bounds__(256) void k_kvpart(const float* __restrict__ kin,
                                                const float* __restrict__ vin,
                                                float* __restrict__ kv,
                                                float* __restrict__ ksum)
{
    __shared__ float fk[64][132];
    __shared__ float vv[64][132];
    const int ch = blockIdx.x, h = blockIdx.y, t = threadIdx.x;
    const int l0 = ch * 64;
    {   // stage 64 rows of K and V (fp32)
        const int lr = t >> 2, cs = (t & 3) * 32;
        const float* ks = kin + ((long)((l0 + lr) * NH + h)) * DH + cs;
        const float* vs = vin + ((long)((l0 + lr) * NH + h)) * DH + cs;
#pragma unroll
        for (int j = 0; j < 8; ++j) {
            float4 a = ((const float4*)ks)[j];
            float4 b = ((const float4*)vs)[j];
            float* kd = &fk[lr][cs + 4 * j];
            float* vd = &vv[lr][cs + 4 * j];
            kd[0] = a.x; kd[1] = a.y; kd[2] = a.z; kd[3] = a.w;
            vd[0] = b.x; vd[1] = b.y; vd[2] = b.z; vd[3] = b.w;
        }
    }
    __syncthreads();
    {   // softmax: 4 threads per row, 32 cols each, shuffle-reduce over 4 lanes
        const int row = t >> 2, cs = (t & 3) * 32;
        float mx = -__builtin_inff();
#pragma unroll 8
        for (int c = 0; c < 32; ++c) mx = fmaxf(mx, fk[row][cs + c]);
        mx = fmaxf(mx, __shfl_xor(mx, 1));
        mx = fmaxf(mx, __shfl_xor(mx, 2));
        float sm = 0.f;
#pragma unroll 8
        for (int c = 0; c < 32; ++c) { float e = __expf(fk[row][cs + c] - mx); fk[row][cs + c] = e; sm += e; }
        sm += __shfl_xor(sm, 1);
        sm += __shfl_xor(sm, 2);
        float inv = 1.f / sm;
#pragma unroll 8
        for (int c = 0; c < 32; ++c) fk[row][cs + c] *= inv;
    }
    __syncthreads();
    const int ci = t & 15, di = t >> 4;
    float acc[8][8];
#pragma unroll
    for (int i = 0; i < 8; ++i)
#pragma unroll
        for (int j = 0; j < 8; ++j) acc[i][j] = 0.f;
    float ks8[8] = {0.f, 0.f, 0.f, 0.f, 0.f, 0.f, 0.f, 0.f};
    for (int l = 0; l < 64; ++l) {
        float4 a0 = *(const float4*)&fk[l][ci * 8];
        float4 a1 = *(const float4*)&fk[l][ci * 8 + 4];
        float4 b0 = *(const float4*)&vv[l][di * 8];
        float4 b1 = *(const float4*)&vv[l][di * 8 + 4];
        float av[8] = {a0.x, a0.y, a0.z, a0.w, a1.x, a1.y, a1.z, a1.w};
        float bv[8] = {b0.x, b0.y, b0.z, b0.w, b1.x, b1.y, b1.z, b1.w};
#pragma unroll
        for (int i = 0; i < 8; ++i)
#pragma unroll
            for (int j = 0; j < 8; ++j) acc[i][j] += av[i] * bv[j];
        if (di == 0) {
#pragma unroll
            for (int i = 0; i < 8; ++i) ks8[i] += av[i];
        }
    }
    float* dst = kv + (long)h * DH * DH + (ci * 8) * DH + di * 8;
#pragma unroll
    for (int i = 0; i < 8; ++i)
#pragma unroll
        for (int j = 0; j < 8; ++j) atomicAdd(dst + i * DH + j, acc[i][j]);
    if (di == 0) {
#pragma unroll
        for (int i = 0; i < 8; ++i) atomicAdd(ksum + h * DH + ci * 8 + i, ks8[i]);
    }
}

// ---------------- M[h][c][e] = sum_d kv[h][c][d]*W[e][d] ----------------
__global__ __launch_bounds__(128) void k_reduce_m(const float* __restrict__ kv,
                                                  const float* __restrict__ w,
                                                  float* __restrict__ M)
{
    __shared__ float kvrow[128];
    const int c = blockIdx.x, h = blockIdx.y, t = threadIdx.x;
    kvrow[t] = kv[(long)h * DH * DH + (long)c * DH + t];
    __syncthreads();
    const float* wr = w + (long)t * DH;
    float m = 0.f;
    for (int d = 0; d < 128; ++d) m += kvrow[d] * wr[d];
    M[((long)(h * DH + c)) * DH + t] = m;
}

// ---------------- linear apply (writes d_out) ----------------
__global__ __launch_bounds__(256) void k_linear(const float* __restrict__ q,
                                                const float* __restrict__ M,
                                                const float* __restrict__ ksum,
                                                const float* __restrict__ bproj,
                                                float* __restrict__ out)
{
    __shared__ float fq[16][132];
    __shared__ float den[16];
    const int lb = blockIdx.x, h = blockIdx.y, t = threadIdx.x;
    const int l0 = lb * 16;
    {
        const int r = t >> 4, c0 = (t & 15) * 8;
        const float4* src = (const float4*)(q + ((long)((l0 + r) * NH + h)) * DH + c0);
        float4 a = src[0], b = src[1];
        float* dst = &fq[r][c0];
        dst[0] = a.x; dst[1] = a.y; dst[2] = a.z; dst[3] = a.w;
        dst[4] = b.x; dst[5] = b.y; dst[6] = b.z; dst[7] = b.w;
    }
    __syncthreads();
    {   // softmax + den: 16 threads per row, 8 cols each
        const int row = t >> 4, sl = t & 15;
        float* fr = &fq[row][sl * 8];
        float mx = -__builtin_inff();
#pragma unroll
        for (int c = 0; c < 8; ++c) mx = fmaxf(mx, fr[c]);
        mx = fmaxf(mx, __shfl_xor(mx, 1));
        mx = fmaxf(mx, __shfl_xor(mx, 2));
        mx = fmaxf(mx, __shfl_xor(mx, 4));
        mx = fmaxf(mx, __shfl_xor(mx, 8));
        float sm = 0.f;
#pragma unroll
        for (int c = 0; c < 8; ++c) { float e = __expf(fr[c] - mx); fr[c] = e; sm += e; }
        sm += __shfl_xor(sm, 1);
        sm += __shfl_xor(sm, 2);
        sm += __shfl_xor(sm, 4);
        sm += __shfl_xor(sm, 8);
        float inv = 1.f / sm;
        const float* ks = ksum + h * DH + sl * 8;
        float dd = 0.f;
#pragma unroll
        for (int c = 0; c < 8; ++c) { float v2 = fr[c] * inv; fr[c] = v2; dd += v2 * ks[c]; }
        dd += __shfl_xor(dd, 1);
        dd += __shfl_xor(dd, 2);
        dd += __shfl_xor(dd, 4);
        dd += __shfl_xor(dd, 8);
        if (sl == 0) den[row] = 1e-5f + dd;
    }
    __syncthreads();
    const int e = t & 127, rg = t >> 7;
    float acc[8] = {0.f, 0.f, 0.f, 0.f, 0.f, 0.f, 0.f, 0.f};
    const float* Mh = M + (long)h * DH * DH + e;
#pragma unroll 4
    for (int c = 0; c < 128; ++c) {
        float m = Mh[(long)c * DH];
#pragma unroll
        for (int rr = 0; rr < 8; ++rr) acc[rr] += fq[rg * 8 + rr][c] * m;
    }
    const float b = bproj[e];
#pragma unroll
    for (int rr = 0; rr < 8; ++rr) {
        const int l = l0 + rg * 8 + rr;
        out[((long)(l * NH + h)) * DH + e] = acc[rr] / den[rg * 8 + rr] + b;
    }
}

// ---------------- sparse flash attention: 8 waves, in-block split-K ----------------
// waves 0-3 (group 0): topk[0..15], waves 4-7 (group 1): topk[16..31],
// all over the same 128 Q rows; flash-merge of the two halves via LDS at the end.
// Each tile is 8192 elems = 1024 b128 slots; 512 threads stage TWO slots each
// (R2 bug: staged only one -> half the tile was garbage).
#define SM_K0   0
#define SM_K1   17408
#define SM_V0   34816
#define SM_V1   53248
#define SM_P    71680
#define SM_LUT  108544
#define SM_SZ   108672
__global__ __launch_bounds__(512, 2) void k_sparse(const float* __restrict__ q,
                                                   const __bf16* __restrict__ kb16,
                                                   const __bf16* __restrict__ vt16,
                                                   const int* __restrict__ lut,
                                                   float* __restrict__ out)
{
    __shared__ __align__(16) char smem[SM_SZ];
    __bf16* K0 = (__bf16*)(smem + SM_K0);   // [64][136]
    __bf16* K1 = (__bf16*)(smem + SM_K1);
    __bf16* V0 = (__bf16*)(smem + SM_V0);   // [128][72]
    __bf16* V1 = (__bf16*)(smem + SM_V1);
    int* luts  = (int*)(smem + SM_LUT);

    const int qb = blockIdx.x, h = blockIdx.y;
    const int t = threadIdx.x;
    const int w = t >> 6;
    const int lane = t & 63;
    const int l16 = lane & 15;
    const int quad = lane >> 4;
    const int g = w >> 2;      // K-half group
    const int wg = w & 3;      // wave-in-group -> row base wg*32

    if (t < 32) luts[t] = lut[(h * NQB + qb) * TOPK + t];

    // Q fragments (A-layout) for rows qb*128 + wg*32 + mt*16 + l16
    bf16x8 qf[2][4];
#pragma unroll
    for (int mt = 0; mt < 2; ++mt) {
        const int gl = qb * 128 + wg * 32 + mt * 16 + l16;
        const float* qrow = q + ((long)(gl * NH + h)) * DH;
#pragma unroll
        for (int ks = 0; ks < 4; ++ks) {
            const float4* s2 = (const float4*)(qrow + ks * 32 + quad * 8);
            float4 a = s2[0], b = s2[1];
            bf16x8 f;
            f[0] = (__bf16)a.x; f[1] = (__bf16)a.y; f[2] = (__bf16)a.z; f[3] = (__bf16)a.w;
            f[4] = (__bf16)b.x; f[5] = (__bf16)b.y; f[6] = (__bf16)b.z; f[7] = (__bf16)b.w;
            qf[mt][ks] = f;
        }
    }

    const floatx4 vzero = {0.f, 0.f, 0.f, 0.f};
    floatx4 o_acc[2][8];
#pragma unroll
    for (int mt = 0; mt < 2; ++mt)
#pragma unroll
        for (int nt = 0; nt < 8; ++nt) o_acc[mt][nt] = vzero;
    float mstate[2][4], lstate[2][4];
#pragma unroll
    for (int mt = 0; mt < 2; ++mt)
#pragma unroll
        for (int r = 0; r < 4; ++r) { mstate[mt][r] = -__builtin_inff(); lstate[mt][r] = 0.f; }

    const float scale = 0.08838834764831845f;  // 1/sqrt(128)
    const __bf16* kbh = kb16 + (long)h * L_SEQ * DH;
    const __bf16* vth = vt16 + (long)h * DH * L_SEQ;
    // slot mapping: slots t and t+512 of 1024 per tile
    int kr[2], kc8[2], vr[2], vc8[2];
#pragma unroll
    for (int j = 0; j < 2; ++j) {
        const int si = t + j * 512;
        kr[j] = si >> 4; kc8[j] = si & 15;   // K tile [64][128]: 16 slots/row
        vr[j] = si >> 3; vc8[j] = si & 7;    // V tile [128][64]: 8 slots/row
    }
    const __bf16* Kg = g ? K1 : K0;
    const __bf16* Vg = g ? V1 : V0;
    __bf16* Pw = (__bf16*)(smem + SM_P) + w * (32 * 72);

    __syncthreads();   // luts ready

    // prefetch iteration 0 tiles into registers
    bf16x8 pk0[2], pk1[2], pv0[2], pv1[2];
    {
        const int b0 = luts[0], b1 = luts[16];
#pragma unroll
        for (int j = 0; j < 2; ++j) {
            pk0[j] = *(const bf16x8*)(kbh + ((long)(b0 * 64 + kr[j])) * DH + kc8[j] * 8);
            pk1[j] = *(const bf16x8*)(kbh + ((long)(b1 * 64 + kr[j])) * DH + kc8[j] * 8);
            pv0[j] = *(const bf16x8*)(vth + (long)vr[j] * L_SEQ + b0 * 64 + vc8[j] * 8);
            pv1[j] = *(const bf16x8*)(vth + (long)vr[j] * L_SEQ + b1 * 64 + vc8[j] * 8);
        }
    }

    for (int it = 0; it < 16; ++it) {
        // tiles are free (post-barrier): commit prefetched regs to LDS
#pragma unroll
        for (int j = 0; j < 2; ++j) {
            *(bf16x8*)(K0 + kr[j] * 136 + kc8[j] * 8) = pk0[j];
            *(bf16x8*)(K1 + kr[j] * 136 + kc8[j] * 8) = pk1[j];
            *(bf16x8*)(V0 + vr[j] * 72 + vc8[j] * 8)  = pv0[j];
            *(bf16x8*)(V1 + vr[j] * 72 + vc8[j] * 8)  = pv1[j];
        }
        __syncthreads();   // tiles ready
        if (it < 15) {     // issue next iteration's loads; latency hidden by compute
            const int b0 = luts[it + 1], b1 = luts[16 + it + 1];
#pragma unroll
            for (int j = 0; j < 2; ++j) {
                pk0[j] = *(const bf16x8*)(kbh + ((long)(b0 * 64 + kr[j])) * DH + kc8[j] * 8);
                pk1[j] = *(const bf16x8*)(kbh + ((long)(b1 * 64 + kr[j])) * DH + kc8[j] * 8);
                pv0[j] = *(const bf16x8*)(vth + (long)vr[j] * L_SEQ + b0 * 64 + vc8[j] * 8);
                pv1[j] = *(const bf16x8*)(vth + (long)vr[j] * L_SEQ + b1 * 64 + vc8[j] * 8);
            }
        }

        // S = Q @ K^T (32 rows x 64 keys per wave)
        floatx4 sfr[2][4];
#pragma unroll
        for (int mt = 0; mt < 2; ++mt)
#pragma unroll
            for (int nt = 0; nt < 4; ++nt) sfr[mt][nt] = vzero;
#pragma unroll
        for (int ks = 0; ks < 4; ++ks) {
            bf16x8 bf[4];
#pragma unroll
            for (int nt = 0; nt < 4; ++nt)
                bf[nt] = *(const bf16x8*)(Kg + (nt * 16 + l16) * 136 + ks * 32 + quad * 8);
#pragma unroll
            for (int mt = 0; mt < 2; ++mt)
#pragma unroll
                for (int nt = 0; nt < 4; ++nt)
                    sfr[mt][nt] = __builtin_amdgcn_mfma_f32_16x16x32_bf16(qf[mt][ks], bf[nt], sfr[mt][nt], 0, 0, 0);
        }

        // online softmax; P -> per-wave LDS (wave-local round-trip)
#pragma unroll
        for (int mt = 0; mt < 2; ++mt) {
#pragma unroll
            for (int r = 0; r < 4; ++r) {
                float s0 = sfr[mt][0][r] * scale;
                float s1 = sfr[mt][1][r] * scale;
                float s2 = sfr[mt][2][r] * scale;
                float s3 = sfr[mt][3][r] * scale;
                float vmax = fmaxf(fmaxf(s0, s1), fmaxf(s2, s3));
                vmax = fmaxf(vmax, __shfl_xor(vmax, 1));
                vmax = fmaxf(vmax, __shfl_xor(vmax, 2));
                vmax = fmaxf(vmax, __shfl_xor(vmax, 4));
                vmax = fmaxf(vmax, __shfl_xor(vmax, 8));
                const float mold = mstate[mt][r];
                const float mnew = fmaxf(mold, vmax);
                mstate[mt][r] = mnew;
                const float alpha = __expf(mold - mnew);
                float p0 = __expf(s0 - mnew);
                float p1 = __expf(s1 - mnew);
                float p2 = __expf(s2 - mnew);
                float p3 = __expf(s3 - mnew);
                float rsum = (p0 + p1) + (p2 + p3);
                rsum += __shfl_xor(rsum, 1);
                rsum += __shfl_xor(rsum, 2);
                rsum += __shfl_xor(rsum, 4);
                rsum += __shfl_xor(rsum, 8);
                lstate[mt][r] = lstate[mt][r] * alpha + rsum;
#pragma unroll
                for (int nt = 0; nt < 8; ++nt) o_acc[mt][nt][r] *= alpha;
                __bf16* pb = Pw + (mt * 16 + quad * 4 + r) * 72 + l16;
                pb[0]  = (__bf16)p0;
                pb[16] = (__bf16)p1;
                pb[32] = (__bf16)p2;
                pb[48] = (__bf16)p3;
            }
        }

        // O += P @ V
#pragma unroll
        for (int ks2 = 0; ks2 < 2; ++ks2) {
            bf16x8 af[2];
#pragma unroll
            for (int mt = 0; mt < 2; ++mt)
                af[mt] = *(const bf16x8*)(Pw + (mt * 16 + l16) * 72 + ks2 * 32 + quad * 8);
#pragma unroll
            for (int nt = 0; nt < 8; ++nt) {
                bf16x8 bv = *(const bf16x8*)(Vg + (nt * 16 + l16) * 72 + ks2 * 32 + quad * 8);
#pragma unroll
                for (int mt = 0; mt < 2; ++mt)
                    o_acc[mt][nt] = __builtin_amdgcn_mfma_f32_16x16x32_bf16(af[mt], bv, o_acc[mt][nt], 0, 0, 0);
            }
        }
        __syncthreads();   // all waves done reading tiles -> safe to overwrite
    }

    // ---- merge the two K-halves (flash combine), then out += ----
    float* O1  = (float*)smem;               // [128][132] fp32, reuses tile region
    float* mlm = (float*)(smem + SM_P);      // [128], reuses P region
    float* mll = mlm + 128;
    if (g == 1) {
#pragma unroll
        for (int mt = 0; mt < 2; ++mt) {
#pragma unroll
            for (int r = 0; r < 4; ++r) {
                const int row = wg * 32 + mt * 16 + quad * 4 + r;
                if (l16 == 0) { mlm[row] = mstate[mt][r]; mll[row] = lstate[mt][r]; }
#pragma unroll
                for (int nt = 0; nt < 8; ++nt)
                    O1[row * 132 + nt * 16 + l16] = o_acc[mt][nt][r];
            }
        }
    }
    __syncthreads();
    if (g == 0) {
#pragma unroll
        for (int mt = 0; mt < 2; ++mt) {
#pragma unroll
            for (int r = 0; r < 4; ++r) {
                const int row = wg * 32 + mt * 16 + quad * 4 + r;
                const float m0 = mstate[mt][r], l0 = lstate[mt][r];
                const float m1 = mlm[row], l1 = mll[row];
                const float mm = fmaxf(m0, m1);
                const float a0 = __expf(m0 - mm), a1 = __expf(m1 - mm);
                const float inv = 1.f / (l0 * a0 + l1 * a1);
                const int gl = qb * 128 + row;
#pragma unroll
                for (int nt = 0; nt < 8; ++nt) {
                    const int e = nt * 16 + l16;
                    const long idx = ((long)(gl * NH + h)) * DH + e;
                    out[idx] += (o_acc[mt][nt][r] * a0 + O1[row * 132 + e] * a1) * inv;
                }
            }
        }
    }
}

extern "C" void kernel_launch(void* const* d_in, const int* in_sizes, int n_in,
                              void* d_out, int out_size, void* d_ws, size_t ws_size,
                              hipStream_t stream)
{
    const float* q = (const float*)d_in[0];
    const float* k = (const float*)d_in[1];
    const float* v = (const float*)d_in[2];
    const float* w = (const float*)d_in[3];
    const float* b = (const float*)d_in[4];
    float* out = (float*)d_out;
    char* ws = (char*)d_ws;

    // workspace layout (18.3 MB)
    __bf16* kb16 = (__bf16*)(ws + 0);          //  8,388,608  K bf16 [h][l][d]
    __bf16* vt16 = (__bf16*)(ws + 8388608);    //  8,388,608  V bf16 [h][d][l]
    float*  pq   = (float*)(ws + 16777216);    //    131,072
    float*  pks  = (float*)(ws + 16908288);    //    262,144
    int*    lut  = (int*)  (ws + 17170432);    //     32,768
    float*  kv   = (float*)(ws + 17203200);    //    524,288  kv accumulator [h][c][d]
    float*  ksum = (float*)(ws + 17727488);    //      4,096  (contiguous with kv)
    float*  M    = (float*)(ws + 17731584);    //    524,288  kv @ W^T

    hipMemsetAsync(kv, 0, 524288 + 4096, stream);   // zero atomic accumulators

    k_convert_k  <<<dim3(2048),   dim3(256), 0, stream>>>(k, kb16);
    k_transpose_v<<<dim3(64, 8),  dim3(256), 0, stream>>>(v, vt16);
    k_pool       <<<dim3(96, 8),  dim3(128), 0, stream>>>(q, k, pq, pks);
    k_route      <<<dim3(32, 8),  dim3(64),  0, stream>>>(pq, pks, lut);
    k_kvpart     <<<dim3(64, 8),  dim3(256), 0, stream>>>(k, v, kv, ksum);
    k_reduce_m   <<<dim3(128, 8), dim3(128), 0, stream>>>(kv, w, M);
    k_linear     <<<dim3(256, 8), dim3(256), 0, stream>>>(q, M, ksum, b, out);   // writes d_out
    k_sparse     <<<dim3(32, 8),  dim3(512), 0, stream>>>(q, kb16, vt16, lut, out); // += sparse
}

// Round 4
// 289.286 us; speedup vs baseline: 1.6865x; 1.6865x over previous
//
#include <hip/hip_runtime.h>
#include <hip/hip_bf16.h>

#define L_SEQ 4096
#define NH 8
#define DH 128
#define NQB 32
#define NKB 64
#define TOPK 32
#define KVCH 16   // kv partial chunks per head

typedef __bf16 bf16x8 __attribute__((ext_vector_type(8)));
typedef float floatx4 __attribute__((ext_vector_type(4)));

static_assert(sizeof(bf16x8) == 16, "bf16x8 must be 16B");

// ---------------- K -> bf16 [h][l][d] ----------------
__global__ __launch_bounds__(256) void k_convert_k(const float* __restrict__ kin,
                                                   __bf16* __restrict__ kb)
{
    int t = blockIdx.x * 256 + threadIdx.x;
    long base = (long)t * 8;                     // flat [l][h][d]
    int d  = (int)(base & 127);
    int lh = (int)(base >> 7);
    int h  = lh & 7;
    int l  = lh >> 3;
    const float4* s = (const float4*)(kin + base);
    float4 a = s[0], b = s[1];
    bf16x8 o;
    o[0] = (__bf16)a.x; o[1] = (__bf16)a.y; o[2] = (__bf16)a.z; o[3] = (__bf16)a.w;
    o[4] = (__bf16)b.x; o[5] = (__bf16)b.y; o[6] = (__bf16)b.z; o[7] = (__bf16)b.w;
    *(bf16x8*)(kb + ((long)(h * L_SEQ + l)) * DH + d) = o;
}

// ---------------- V -> bf16 transposed [h][d][l] ----------------
__global__ __launch_bounds__(256) void k_transpose_v(const float* __restrict__ vin,
                                                     __bf16* __restrict__ vt)
{
    __shared__ float tile[64][129];
    const int lb = blockIdx.x, h = blockIdx.y, t = threadIdx.x;
    {
        const int r = t >> 2, seg = (t & 3) * 32;
        const float* src = vin + ((long)((lb * 64 + r) * NH + h)) * DH + seg;
#pragma unroll
        for (int j = 0; j < 8; ++j) {
            float4 x = ((const float4*)src)[j];
            float* dstp = &tile[r][seg + 4 * j];
            dstp[0] = x.x; dstp[1] = x.y; dstp[2] = x.z; dstp[3] = x.w;
        }
    }
    __syncthreads();
    {
        const int d = t >> 1, lh2 = (t & 1) * 32;
        bf16x8 ov[4];
#pragma unroll
        for (int i = 0; i < 32; ++i) ov[i >> 3][i & 7] = (__bf16)tile[lh2 + i][d];
        bf16x8* dst = (bf16x8*)(vt + ((long)(h * DH + d)) * L_SEQ + lb * 64 + lh2);
#pragma unroll
        for (int j = 0; j < 4; ++j) dst[j] = ov[j];
    }
}

// ---------------- block pooling ----------------
__global__ __launch_bounds__(128) void k_pool(const float* __restrict__ q,
                                              const float* __restrict__ k,
                                              float* __restrict__ pq,
                                              float* __restrict__ pks)
{
    const int y = blockIdx.x, h = blockIdx.y, d = threadIdx.x;
    if (y < NKB) {
        float acc = 0.f;
        const int l0 = y * 64;
        for (int r = 0; r < 64; ++r) acc += k[((long)((l0 + r) * NH + h)) * DH + d];
        pks[((long)(h * NKB + y)) * DH + d] = acc;
    } else {
        const int qb = y - NKB;
        float acc = 0.f;
        const int l0 = qb * 128;
        for (int r = 0; r < 128; ++r) acc += q[((long)((l0 + r) * NH + h)) * DH + d];
        pq[((long)(h * NQB + qb)) * DH + d] = acc;
    }
}

// ---------------- routing: rank-based top-32 ----------------
__global__ __launch_bounds__(64) void k_route(const float* __restrict__ pq,
                                              const float* __restrict__ pks,
                                              int* __restrict__ lut)
{
    __shared__ float qv[128];
    __shared__ float sc[64];
    const int qi = blockIdx.x, h = blockIdx.y, j = threadIdx.x;
    qv[j]      = pq[((long)(h * NQB + qi)) * DH + j];
    qv[j + 64] = pq[((long)(h * NQB + qi)) * DH + j + 64];
    __syncthreads();
    const float* pr = pks + ((long)(h * NKB + j)) * DH;
    float s = 0.f;
    for (int d = 0; d < 128; ++d) s += qv[d] * pr[d];
    sc[j] = s;
    __syncthreads();
    int rank = 0;
    for (int j2 = 0; j2 < 64; ++j2) {
        float o = sc[j2];
        rank += (o > s) || (o == s && j2 < j);
    }
    if (rank < TOPK) lut[(h * NQB + qi) * TOPK + rank] = j;
}

// ---------------- kv partials: NO atomics (R3 lesson: 8.4M device atomics = 256us).
// 128 blocks; each does 256 rows via 4x 64-row LDS sub-tiles, accumulates the
// 8x8 register tile across all rows, writes ONE partial. ----------------
__global__ __launch_bounds__(256) void k_kvpart(const float* __restrict__ kin,
                                                const float* __restrict__ vin,
                                                float* __restrict__ kvp,
                                                float* __restrict__ ksp)
{
    __shared__ float fk[64][132];
    __shared__ float vv[64][132];
    const int ch = blockIdx.x, h = blockIdx.y, t = threadIdx.x;
    const int ci = t & 15, di = t >> 4;
    const int lr = t >> 2, cs = (t & 3) * 32;
    float acc[8][8];
#pragma unroll
    for (int i = 0; i < 8; ++i)
#pragma unroll
        for (int j = 0; j < 8; ++j) acc[i][j] = 0.f;
    float ks8[8] = {0.f, 0.f, 0.f, 0.f, 0.f, 0.f, 0.f, 0.f};

    for (int sub = 0; sub < 4; ++sub) {
        const int l0 = ch * 256 + sub * 64;
        __syncthreads();   // previous sub's LDS readers done
        {   // stage 64 rows of K and V (fp32)
            const float* ks = kin + ((long)((l0 + lr) * NH + h)) * DH + cs;
            const float* vs = vin + ((long)((l0 + lr) * NH + h)) * DH + cs;
#pragma unroll
            for (int j = 0; j < 8; ++j) {
                float4 a = ((const float4*)ks)[j];
                float4 b = ((const float4*)vs)[j];
                float* kd = &fk[lr][cs + 4 * j];
                float* vd = &vv[lr][cs + 4 * j];
                kd[0] = a.x; kd[1] = a.y; kd[2] = a.z; kd[3] = a.w;
                vd[0] = b.x; vd[1] = b.y; vd[2] = b.z; vd[3] = b.w;
            }
        }
        __syncthreads();
        {   // softmax: 4 threads per row, 32 cols each, shuffle-reduce over 4 lanes
            const int row = t >> 2, cs2 = (t & 3) * 32;
            float mx = -__builtin_inff();
#pragma unroll 8
            for (int c = 0; c < 32; ++c) mx = fmaxf(mx, fk[row][cs2 + c]);
            mx = fmaxf(mx, __shfl_xor(mx, 1));
            mx = fmaxf(mx, __shfl_xor(mx, 2));
            float sm = 0.f;
#pragma unroll 8
            for (int c = 0; c < 32; ++c) { float e = __expf(fk[row][cs2 + c] - mx); fk[row][cs2 + c] = e; sm += e; }
            sm += __shfl_xor(sm, 1);
            sm += __shfl_xor(sm, 2);
            float inv = 1.f / sm;
#pragma unroll 8
            for (int c = 0; c < 32; ++c) fk[row][cs2 + c] *= inv;
        }
        __syncthreads();
        for (int l = 0; l < 64; ++l) {
            float4 a0 = *(const float4*)&fk[l][ci * 8];
            float4 a1 = *(const float4*)&fk[l][ci * 8 + 4];
            float4 b0 = *(const float4*)&vv[l][di * 8];
            float4 b1 = *(const float4*)&vv[l][di * 8 + 4];
            float av[8] = {a0.x, a0.y, a0.z, a0.w, a1.x, a1.y, a1.z, a1.w};
            float bv[8] = {b0.x, b0.y, b0.z, b0.w, b1.x, b1.y, b1.z, b1.w};
#pragma unroll
            for (int i = 0; i < 8; ++i)
#pragma unroll
                for (int j = 0; j < 8; ++j) acc[i][j] += av[i] * bv[j];
            if (di == 0) {
#pragma unroll
                for (int i = 0; i < 8; ++i) ks8[i] += av[i];
            }
        }
    }
    float* dst = kvp + (((long)(h * KVCH + ch) * 128) + ci * 8) * 128 + di * 8;
#pragma unroll
    for (int i = 0; i < 8; ++i) {
        float4 w0 = {acc[i][0], acc[i][1], acc[i][2], acc[i][3]};
        float4 w1 = {acc[i][4], acc[i][5], acc[i][6], acc[i][7]};
        ((float4*)(dst + (long)i * 128))[0] = w0;
        ((float4*)(dst + (long)i * 128))[1] = w1;
    }
    if (di == 0) {
        float* kd2 = ksp + (h * KVCH + ch) * 128 + ci * 8;
#pragma unroll
        for (int i = 0; i < 8; ++i) kd2[i] = ks8[i];
    }
}

// ---------------- reduce partials; M[h][c][e] = sum_d kv[c][d]*W[e][d]; ksum ----------------
__global__ __launch_bounds__(128) void k_reduce_m(const float* __restrict__ kvp,
                                                  const float* __restrict__ ksp,
                                                  const float* __restrict__ w,
                                                  float* __restrict__ M,
                                                  float* __restrict__ ksum)
{
    __shared__ float kvrow[128];
    const int c = blockIdx.x, h = blockIdx.y, t = threadIdx.x;
    float acc = 0.f;
    for (int ch = 0; ch < KVCH; ++ch)
        acc += kvp[(((long)(h * KVCH + ch) * 128) + c) * 128 + t];
    kvrow[t] = acc;
    if (t == 0) {
        float s = 0.f;
        for (int ch = 0; ch < KVCH; ++ch) s += ksp[(h * KVCH + ch) * 128 + c];
        ksum[h * 128 + c] = s;
    }
    __syncthreads();
    const float* wr = w + (long)t * DH;
    float m = 0.f;
    for (int d = 0; d < 128; ++d) m += kvrow[d] * wr[d];
    M[((long)(h * DH + c)) * DH + t] = m;
}

// ---------------- linear apply (writes d_out) ----------------
__global__ __launch_bounds__(256) void k_linear(const float* __restrict__ q,
                                                const float* __restrict__ M,
                                                const float* __restrict__ ksum,
                                                const float* __restrict__ bproj,
                                                float* __restrict__ out)
{
    __shared__ float fq[16][132];
    __shared__ float den[16];
    const int lb = blockIdx.x, h = blockIdx.y, t = threadIdx.x;
    const int l0 = lb * 16;
    {
        const int r = t >> 4, c0 = (t & 15) * 8;
        const float4* src = (const float4*)(q + ((long)((l0 + r) * NH + h)) * DH + c0);
        float4 a = src[0], b = src[1];
        float* dst = &fq[r][c0];
        dst[0] = a.x; dst[1] = a.y; dst[2] = a.z; dst[3] = a.w;
        dst[4] = b.x; dst[5] = b.y; dst[6] = b.z; dst[7] = b.w;
    }
    __syncthreads();
    {   // softmax + den: 16 threads per row, 8 cols each
        const int row = t >> 4, sl = t & 15;
        float* fr = &fq[row][sl * 8];
        float mx = -__builtin_inff();
#pragma unroll
        for (int c = 0; c < 8; ++c) mx = fmaxf(mx, fr[c]);
        mx = fmaxf(mx, __shfl_xor(mx, 1));
        mx = fmaxf(mx, __shfl_xor(mx, 2));
        mx = fmaxf(mx, __shfl_xor(mx, 4));
        mx = fmaxf(mx, __shfl_xor(mx, 8));
        float sm = 0.f;
#pragma unroll
        for (int c = 0; c < 8; ++c) { float e = __expf(fr[c] - mx); fr[c] = e; sm += e; }
        sm += __shfl_xor(sm, 1);
        sm += __shfl_xor(sm, 2);
        sm += __shfl_xor(sm, 4);
        sm += __shfl_xor(sm, 8);
        float inv = 1.f / sm;
        const float* ks = ksum + h * DH + sl * 8;
        float dd = 0.f;
#pragma unroll
        for (int c = 0; c < 8; ++c) { float v2 = fr[c] * inv; fr[c] = v2; dd += v2 * ks[c]; }
        dd += __shfl_xor(dd, 1);
        dd += __shfl_xor(dd, 2);
        dd += __shfl_xor(dd, 4);
        dd += __shfl_xor(dd, 8);
        if (sl == 0) den[row] = 1e-5f + dd;
    }
    __syncthreads();
    const int e = t & 127, rg = t >> 7;
    float acc[8] = {0.f, 0.f, 0.f, 0.f, 0.f, 0.f, 0.f, 0.f};
    const float* Mh = M + (long)h * DH * DH + e;
#pragma unroll 4
    for (int c = 0; c < 128; ++c) {
        float m = Mh[(long)c * DH];
#pragma unroll
        for (int rr = 0; rr < 8; ++rr) acc[rr] += fq[rg * 8 + rr][c] * m;
    }
    const float b = bproj[e];
#pragma unroll
    for (int rr = 0; rr < 8; ++rr) {
        const int l = l0 + rg * 8 + rr;
        out[((long)(l * NH + h)) * DH + e] = acc[rr] / den[rg * 8 + rr] + b;
    }
}

// ---------------- sparse flash attention: 8 waves, in-block split-K ----------------
// waves 0-3 (group 0): topk[0..15], waves 4-7 (group 1): topk[16..31],
// all over the same 128 Q rows; flash-merge of the two halves via LDS at the end.
#define SM_K0   0
#define SM_K1   17408
#define SM_V0   34816
#define SM_V1   53248
#define SM_P    71680
#define SM_LUT  108544
#define SM_SZ   108672
__global__ __launch_bounds__(512, 2) void k_sparse(const float* __restrict__ q,
                                                   const __bf16* __restrict__ kb16,
                                                   const __bf16* __restrict__ vt16,
                                                   const int* __restrict__ lut,
                                                   float* __restrict__ out)
{
    __shared__ __align__(16) char smem[SM_SZ];
    __bf16* K0 = (__bf16*)(smem + SM_K0);   // [64][136]
    __bf16* K1 = (__bf16*)(smem + SM_K1);
    __bf16* V0 = (__bf16*)(smem + SM_V0);   // [128][72]
    __bf16* V1 = (__bf16*)(smem + SM_V1);
    int* luts  = (int*)(smem + SM_LUT);

    const int qb = blockIdx.x, h = blockIdx.y;
    const int t = threadIdx.x;
    const int w = t >> 6;
    const int lane = t & 63;
    const int l16 = lane & 15;
    const int quad = lane >> 4;
    const int g = w >> 2;      // K-half group
    const int wg = w & 3;      // wave-in-group -> row base wg*32

    if (t < 32) luts[t] = lut[(h * NQB + qb) * TOPK + t];

    // Q fragments (A-layout) for rows qb*128 + wg*32 + mt*16 + l16
    bf16x8 qf[2][4];
#pragma unroll
    for (int mt = 0; mt < 2; ++mt) {
        const int gl = qb * 128 + wg * 32 + mt * 16 + l16;
        const float* qrow = q + ((long)(gl * NH + h)) * DH;
#pragma unroll
        for (int ks = 0; ks < 4; ++ks) {
            const float4* s2 = (const float4*)(qrow + ks * 32 + quad * 8);
            float4 a = s2[0], b = s2[1];
            bf16x8 f;
            f[0] = (__bf16)a.x; f[1] = (__bf16)a.y; f[2] = (__bf16)a.z; f[3] = (__bf16)a.w;
            f[4] = (__bf16)b.x; f[5] = (__bf16)b.y; f[6] = (__bf16)b.z; f[7] = (__bf16)b.w;
            qf[mt][ks] = f;
        }
    }

    const floatx4 vzero = {0.f, 0.f, 0.f, 0.f};
    floatx4 o_acc[2][8];
#pragma unroll
    for (int mt = 0; mt < 2; ++mt)
#pragma unroll
        for (int nt = 0; nt < 8; ++nt) o_acc[mt][nt] = vzero;
    float mstate[2][4], lstate[2][4];
#pragma unroll
    for (int mt = 0; mt < 2; ++mt)
#pragma unroll
        for (int r = 0; r < 4; ++r) { mstate[mt][r] = -__builtin_inff(); lstate[mt][r] = 0.f; }

    const float scale = 0.08838834764831845f;  // 1/sqrt(128)
    const __bf16* kbh = kb16 + (long)h * L_SEQ * DH;
    const __bf16* vth = vt16 + (long)h * DH * L_SEQ;
    // slot mapping: slots t and t+512 of 1024 per tile
    int kr[2], kc8[2], vr[2], vc8[2];
#pragma unroll
    for (int j = 0; j < 2; ++j) {
        const int si = t + j * 512;
        kr[j] = si >> 4; kc8[j] = si & 15;   // K tile [64][128]: 16 slots/row
        vr[j] = si >> 3; vc8[j] = si & 7;    // V tile [128][64]: 8 slots/row
    }
    const __bf16* Kg = g ? K1 : K0;
    const __bf16* Vg = g ? V1 : V0;
    __bf16* Pw = (__bf16*)(smem + SM_P) + w * (32 * 72);

    __syncthreads();   // luts ready

    // prefetch iteration 0 tiles into registers
    bf16x8 pk0[2], pk1[2], pv0[2], pv1[2];
    {
        const int b0 = luts[0], b1 = luts[16];
#pragma unroll
        for (int j = 0; j < 2; ++j) {
            pk0[j] = *(const bf16x8*)(kbh + ((long)(b0 * 64 + kr[j])) * DH + kc8[j] * 8);
            pk1[j] = *(const bf16x8*)(kbh + ((long)(b1 * 64 + kr[j])) * DH + kc8[j] * 8);
            pv0[j] = *(const bf16x8*)(vth + (long)vr[j] * L_SEQ + b0 * 64 + vc8[j] * 8);
            pv1[j] = *(const bf16x8*)(vth + (long)vr[j] * L_SEQ + b1 * 64 + vc8[j] * 8);
        }
    }

    for (int it = 0; it < 16; ++it) {
        // tiles are free (post-barrier): commit prefetched regs to LDS
#pragma unroll
        for (int j = 0; j < 2; ++j) {
            *(bf16x8*)(K0 + kr[j] * 136 + kc8[j] * 8) = pk0[j];
            *(bf16x8*)(K1 + kr[j] * 136 + kc8[j] * 8) = pk1[j];
            *(bf16x8*)(V0 + vr[j] * 72 + vc8[j] * 8)  = pv0[j];
            *(bf16x8*)(V1 + vr[j] * 72 + vc8[j] * 8)  = pv1[j];
        }
        __syncthreads();   // tiles ready
        if (it < 15) {     // issue next iteration's loads; latency hidden by compute
            const int b0 = luts[it + 1], b1 = luts[16 + it + 1];
#pragma unroll
            for (int j = 0; j < 2; ++j) {
                pk0[j] = *(const bf16x8*)(kbh + ((long)(b0 * 64 + kr[j])) * DH + kc8[j] * 8);
                pk1[j] = *(const bf16x8*)(kbh + ((long)(b1 * 64 + kr[j])) * DH + kc8[j] * 8);
                pv0[j] = *(const bf16x8*)(vth + (long)vr[j] * L_SEQ + b0 * 64 + vc8[j] * 8);
                pv1[j] = *(const bf16x8*)(vth + (long)vr[j] * L_SEQ + b1 * 64 + vc8[j] * 8);
            }
        }

        // S = Q @ K^T (32 rows x 64 keys per wave)
        floatx4 sfr[2][4];
#pragma unroll
        for (int mt = 0; mt < 2; ++mt)
#pragma unroll
            for (int nt = 0; nt < 4; ++nt) sfr[mt][nt] = vzero;
#pragma unroll
        for (int ks = 0; ks < 4; ++ks) {
            bf16x8 bf[4];
#pragma unroll
            for (int nt = 0; nt < 4; ++nt)
                bf[nt] = *(const bf16x8*)(Kg + (nt * 16 + l16) * 136 + ks * 32 + quad * 8);
#pragma unroll
            for (int mt = 0; mt < 2; ++mt)
#pragma unroll
                for (int nt = 0; nt < 4; ++nt)
                    sfr[mt][nt] = __builtin_amdgcn_mfma_f32_16x16x32_bf16(qf[mt][ks], bf[nt], sfr[mt][nt], 0, 0, 0);
        }

        // online softmax; P -> per-wave LDS (wave-local round-trip)
#pragma unroll
        for (int mt = 0; mt < 2; ++mt) {
#pragma unroll
            for (int r = 0; r < 4; ++r) {
                float s0 = sfr[mt][0][r] * scale;
                float s1 = sfr[mt][1][r] * scale;
                float s2 = sfr[mt][2][r] * scale;
                float s3 = sfr[mt][3][r] * scale;
                float vmax = fmaxf(fmaxf(s0, s1), fmaxf(s2, s3));
                vmax = fmaxf(vmax, __shfl_xor(vmax, 1));
                vmax = fmaxf(vmax, __shfl_xor(vmax, 2));
                vmax = fmaxf(vmax, __shfl_xor(vmax, 4));
                vmax = fmaxf(vmax, __shfl_xor(vmax, 8));
                const float mold = mstate[mt][r];
                const float mnew = fmaxf(mold, vmax);
                mstate[mt][r] = mnew;
                const float alpha = __expf(mold - mnew);
                float p0 = __expf(s0 - mnew);
                float p1 = __expf(s1 - mnew);
                float p2 = __expf(s2 - mnew);
                float p3 = __expf(s3 - mnew);
                float rsum = (p0 + p1) + (p2 + p3);
                rsum += __shfl_xor(rsum, 1);
                rsum += __shfl_xor(rsum, 2);
                rsum += __shfl_xor(rsum, 4);
                rsum += __shfl_xor(rsum, 8);
                lstate[mt][r] = lstate[mt][r] * alpha + rsum;
#pragma unroll
                for (int nt = 0; nt < 8; ++nt) o_acc[mt][nt][r] *= alpha;
                __bf16* pb = Pw + (mt * 16 + quad * 4 + r) * 72 + l16;
                pb[0]  = (__bf16)p0;
                pb[16] = (__bf16)p1;
                pb[32] = (__bf16)p2;
                pb[48] = (__bf16)p3;
            }
        }

        // O += P @ V
#pragma unroll
        for (int ks2 = 0; ks2 < 2; ++ks2) {
            bf16x8 af[2];
#pragma unroll
            for (int mt = 0; mt < 2; ++mt)
                af[mt] = *(const bf16x8*)(Pw + (mt * 16 + l16) * 72 + ks2 * 32 + quad * 8);
#pragma unroll
            for (int nt = 0; nt < 8; ++nt) {
                bf16x8 bv = *(const bf16x8*)(Vg + (nt * 16 + l16) * 72 + ks2 * 32 + quad * 8);
#pragma unroll
                for (int mt = 0; mt < 2; ++mt)
                    o_acc[mt][nt] = __builtin_amdgcn_mfma_f32_16x16x32_bf16(af[mt], bv, o_acc[mt][nt], 0, 0, 0);
            }
        }
        __syncthreads();   // all waves done reading tiles -> safe to overwrite
    }

    // ---- merge the two K-halves (flash combine), then out += ----
    float* O1  = (float*)smem;               // [128][132] fp32, reuses tile region
    float* mlm = (float*)(smem + SM_P);      // [128], reuses P region
    float* mll = mlm + 128;
    if (g == 1) {
#pragma unroll
        for (int mt = 0; mt < 2; ++mt) {
#pragma unroll
            for (int r = 0; r < 4; ++r) {
                const int row = wg * 32 + mt * 16 + quad * 4 + r;
                if (l16 == 0) { mlm[row] = mstate[mt][r]; mll[row] = lstate[mt][r]; }
#pragma unroll
                for (int nt = 0; nt < 8; ++nt)
                    O1[row * 132 + nt * 16 + l16] = o_acc[mt][nt][r];
            }
        }
    }
    __syncthreads();
    if (g == 0) {
#pragma unroll
        for (int mt = 0; mt < 2; ++mt) {
#pragma unroll
            for (int r = 0; r < 4; ++r) {
                const int row = wg * 32 + mt * 16 + quad * 4 + r;
                const float m0 = mstate[mt][r], l0 = lstate[mt][r];
                const float m1 = mlm[row], l1 = mll[row];
                const float mm = fmaxf(m0, m1);
                const float a0 = __expf(m0 - mm), a1 = __expf(m1 - mm);
                const float inv = 1.f / (l0 * a0 + l1 * a1);
                const int gl = qb * 128 + row;
#pragma unroll
                for (int nt = 0; nt < 8; ++nt) {
                    const int e = nt * 16 + l16;
                    const long idx = ((long)(gl * NH + h)) * DH + e;
                    out[idx] += (o_acc[mt][nt][r] * a0 + O1[row * 132 + e] * a1) * inv;
                }
            }
        }
    }
}

extern "C" void kernel_launch(void* const* d_in, const int* in_sizes, int n_in,
                              void* d_out, int out_size, void* d_ws, size_t ws_size,
                              hipStream_t stream)
{
    const float* q = (const float*)d_in[0];
    const float* k = (const float*)d_in[1];
    const float* v = (const float*)d_in[2];
    const float* w = (const float*)d_in[3];
    const float* b = (const float*)d_in[4];
    float* out = (float*)d_out;
    char* ws = (char*)d_ws;

    // workspace layout (~26.3 MB)
    __bf16* kb16 = (__bf16*)(ws + 0);          //  8,388,608  K bf16 [h][l][d]
    __bf16* vt16 = (__bf16*)(ws + 8388608);    //  8,388,608  V bf16 [h][d][l]
    float*  pq   = (float*)(ws + 16777216);    //    131,072
    float*  pks  = (float*)(ws + 16908288);    //    262,144
    int*    lut  = (int*)  (ws + 17170432);    //     32,768
    float*  kvp  = (float*)(ws + 17203200);    //  8,388,608  kv partials [h][ch][c][d]
    float*  ksp  = (float*)(ws + 25591808);    //     65,536  ksum partials
    float*  ksum = (float*)(ws + 25657344);    //      4,096
    float*  M    = (float*)(ws + 25661440);    //    524,288  kv @ W^T

    k_convert_k  <<<dim3(2048),    dim3(256), 0, stream>>>(k, kb16);
    k_transpose_v<<<dim3(64, 8),   dim3(256), 0, stream>>>(v, vt16);
    k_pool       <<<dim3(96, 8),   dim3(128), 0, stream>>>(q, k, pq, pks);
    k_route      <<<dim3(32, 8),   dim3(64),  0, stream>>>(pq, pks, lut);
    k_kvpart     <<<dim3(KVCH, 8), dim3(256), 0, stream>>>(k, v, kvp, ksp);
    k_reduce_m   <<<dim3(128, 8),  dim3(128), 0, stream>>>(kvp, ksp, w, M, ksum);
    k_linear     <<<dim3(256, 8),  dim3(256), 0, stream>>>(q, M, ksum, b, out);   // writes d_out
    k_sparse     <<<dim3(32, 8),   dim3(512), 0, stream>>>(q, kb16, vt16, lut, out); // += sparse
}

// Round 5
// 267.679 us; speedup vs baseline: 1.8226x; 1.0807x over previous
//
#include <hip/hip_runtime.h>
#include <hip/hip_bf16.h>

#define L_SEQ 4096
#define NH 8
#define DH 128
#define NQB 32
#define NKB 64
#define TOPK 32
#define KVCH 32   // kv partial chunks per head

typedef __bf16 bf16x8 __attribute__((ext_vector_type(8)));
typedef float floatx4 __attribute__((ext_vector_type(4)));

static_assert(sizeof(bf16x8) == 16, "bf16x8 must be 16B");

// ---------------- fused: K->bf16 [h][l][d]; V->bf16 transposed [h][d][l]; pks ----------------
__global__ __launch_bounds__(256) void k_prep_kv(const float* __restrict__ kin,
                                                 const float* __restrict__ vin,
                                                 __bf16* __restrict__ kb,
                                                 __bf16* __restrict__ vt,
                                                 float* __restrict__ pks)
{
    __shared__ float kt[64][129];
    __shared__ float vtile[64][129];
    const int lb = blockIdx.x, h = blockIdx.y, t = threadIdx.x;
    {
        const int r = t >> 2, seg = (t & 3) * 32;
        const float* ks = kin + ((long)((lb * 64 + r) * NH + h)) * DH + seg;
        const float* vs = vin + ((long)((lb * 64 + r) * NH + h)) * DH + seg;
        float frK[32];
#pragma unroll
        for (int j = 0; j < 8; ++j) {
            float4 a = ((const float4*)ks)[j];
            float4 b = ((const float4*)vs)[j];
            float* kd = &kt[r][seg + 4 * j];
            float* vd = &vtile[r][seg + 4 * j];
            kd[0] = a.x; kd[1] = a.y; kd[2] = a.z; kd[3] = a.w;
            vd[0] = b.x; vd[1] = b.y; vd[2] = b.z; vd[3] = b.w;
            frK[4 * j] = a.x; frK[4 * j + 1] = a.y; frK[4 * j + 2] = a.z; frK[4 * j + 3] = a.w;
        }
        bf16x8* kdst = (bf16x8*)(kb + ((long)(h * L_SEQ + lb * 64 + r)) * DH + seg);
#pragma unroll
        for (int g = 0; g < 4; ++g) {
            bf16x8 o;
#pragma unroll
            for (int e = 0; e < 8; ++e) o[e] = (__bf16)frK[g * 8 + e];
            kdst[g] = o;
        }
    }
    __syncthreads();
    if (t < 128) {   // K block column-sums -> pks
        float s = 0.f;
#pragma unroll 8
        for (int rr = 0; rr < 64; ++rr) s += kt[rr][t];
        pks[((long)(h * NKB + lb)) * DH + t] = s;
    }
    {   // V transpose -> vt16 [h][d][l]
        const int d = t >> 1, lh2 = (t & 1) * 32;
        bf16x8 ov[4];
#pragma unroll
        for (int i = 0; i < 32; ++i) ov[i >> 3][i & 7] = (__bf16)vtile[lh2 + i][d];
        bf16x8* dst = (bf16x8*)(vt + ((long)(h * DH + d)) * L_SEQ + lb * 64 + lh2);
#pragma unroll
        for (int j = 0; j < 4; ++j) dst[j] = ov[j];
    }
}

// ---------------- routing (fused Q-pool): rank-based top-32 ----------------
__global__ __launch_bounds__(256) void k_route(const float* __restrict__ q,
                                               const float* __restrict__ pks,
                                               int* __restrict__ lut)
{
    __shared__ float qv[128];
    __shared__ float qv2[128];
    __shared__ float sc[64];
    const int qi = blockIdx.x, h = blockIdx.y, t = threadIdx.x;
    {   // pooled q: 2 threads per column, 64 rows each
        const int d = t & 127, half = t >> 7;
        float acc = 0.f;
        const int r0 = half * 64;
#pragma unroll 4
        for (int r = 0; r < 64; ++r)
            acc += q[((long)((qi * 128 + r0 + r) * NH + h)) * DH + d];
        if (half == 0) qv[d] = acc; else qv2[d] = acc;
    }
    __syncthreads();
    if (t < 128) qv[t] += qv2[t];
    __syncthreads();
    if (t < 64) {
        const float4* pr = (const float4*)(pks + ((long)(h * NKB + t)) * DH);
        const float4* qp = (const float4*)qv;
        float s = 0.f;
#pragma unroll 8
        for (int d4 = 0; d4 < 32; ++d4) {
            float4 a = qp[d4], b = pr[d4];
            s += a.x * b.x + a.y * b.y + a.z * b.z + a.w * b.w;
        }
        sc[t] = s;
    }
    __syncthreads();
    if (t < 64) {
        const float s = sc[t];
        int rank = 0;
        for (int j2 = 0; j2 < 64; ++j2) {
            float o = sc[j2];
            rank += (o > s) || (o == s && j2 < t);
        }
        if (rank < TOPK) lut[(h * NQB + qi) * TOPK + rank] = t;
    }
}

// ---------------- kv partials (no atomics): 256 blocks, 128 rows each ----------------
__global__ __launch_bounds__(256) void k_kvpart(const float* __restrict__ kin,
                                                const float* __restrict__ vin,
                                                float* __restrict__ kvp,
                                                float* __restrict__ ksp)
{
    __shared__ float fk[64][132];
    __shared__ float vv[64][132];
    const int ch = blockIdx.x, h = blockIdx.y, t = threadIdx.x;
    const int ci = t & 15, di = t >> 4;
    const int lr = t >> 2, cs = (t & 3) * 32;
    float acc[8][8];
#pragma unroll
    for (int i = 0; i < 8; ++i)
#pragma unroll
        for (int j = 0; j < 8; ++j) acc[i][j] = 0.f;
    float ks8[8] = {0.f, 0.f, 0.f, 0.f, 0.f, 0.f, 0.f, 0.f};

    for (int sub = 0; sub < 2; ++sub) {
        const int l0 = ch * 128 + sub * 64;
        __syncthreads();
        {
            const float* ks = kin + ((long)((l0 + lr) * NH + h)) * DH + cs;
            const float* vs = vin + ((long)((l0 + lr) * NH + h)) * DH + cs;
#pragma unroll
            for (int j = 0; j < 8; ++j) {
                float4 a = ((const float4*)ks)[j];
                float4 b = ((const float4*)vs)[j];
                float* kd = &fk[lr][cs + 4 * j];
                float* vd = &vv[lr][cs + 4 * j];
                kd[0] = a.x; kd[1] = a.y; kd[2] = a.z; kd[3] = a.w;
                vd[0] = b.x; vd[1] = b.y; vd[2] = b.z; vd[3] = b.w;
            }
        }
        __syncthreads();
        {   // softmax: 4 threads per row
            const int row = t >> 2, cs2 = (t & 3) * 32;
            float mx = -__builtin_inff();
#pragma unroll 8
            for (int c = 0; c < 32; ++c) mx = fmaxf(mx, fk[row][cs2 + c]);
            mx = fmaxf(mx, __shfl_xor(mx, 1));
            mx = fmaxf(mx, __shfl_xor(mx, 2));
            float sm = 0.f;
#pragma unroll 8
            for (int c = 0; c < 32; ++c) { float e = __expf(fk[row][cs2 + c] - mx); fk[row][cs2 + c] = e; sm += e; }
            sm += __shfl_xor(sm, 1);
            sm += __shfl_xor(sm, 2);
            float inv = 1.f / sm;
#pragma unroll 8
            for (int c = 0; c < 32; ++c) fk[row][cs2 + c] *= inv;
        }
        __syncthreads();
        for (int l = 0; l < 64; ++l) {
            float4 a0 = *(const float4*)&fk[l][ci * 8];
            float4 a1 = *(const float4*)&fk[l][ci * 8 + 4];
            float4 b0 = *(const float4*)&vv[l][di * 8];
            float4 b1 = *(const float4*)&vv[l][di * 8 + 4];
            float av[8] = {a0.x, a0.y, a0.z, a0.w, a1.x, a1.y, a1.z, a1.w};
            float bv[8] = {b0.x, b0.y, b0.z, b0.w, b1.x, b1.y, b1.z, b1.w};
#pragma unroll
            for (int i = 0; i < 8; ++i)
#pragma unroll
                for (int j = 0; j < 8; ++j) acc[i][j] += av[i] * bv[j];
            if (di == 0) {
#pragma unroll
                for (int i = 0; i < 8; ++i) ks8[i] += av[i];
            }
        }
    }
    float* dst = kvp + (((long)(h * KVCH + ch) * 128) + ci * 8) * 128 + di * 8;
#pragma unroll
    for (int i = 0; i < 8; ++i) {
        float4 w0 = {acc[i][0], acc[i][1], acc[i][2], acc[i][3]};
        float4 w1 = {acc[i][4], acc[i][5], acc[i][6], acc[i][7]};
        ((float4*)(dst + (long)i * 128))[0] = w0;
        ((float4*)(dst + (long)i * 128))[1] = w1;
    }
    if (di == 0) {
        float* kd2 = ksp + (h * KVCH + ch) * 128 + ci * 8;
#pragma unroll
        for (int i = 0; i < 8; ++i) kd2[i] = ks8[i];
    }
}

// ---------------- reduce partials; M[h][c][e] = sum_d kv[c][d]*W[e][d]; ksum ----------------
__global__ __launch_bounds__(128) void k_reduce_m(const float* __restrict__ kvp,
                                                  const float* __restrict__ ksp,
                                                  const float* __restrict__ w,
                                                  float* __restrict__ M,
                                                  float* __restrict__ ksum)
{
    __shared__ float kvrow[128];
    const int c = blockIdx.x, h = blockIdx.y, t = threadIdx.x;
    float acc = 0.f;
    for (int ch = 0; ch < KVCH; ++ch)
        acc += kvp[(((long)(h * KVCH + ch) * 128) + c) * 128 + t];
    kvrow[t] = acc;
    if (t == 0) {
        float s = 0.f;
        for (int ch = 0; ch < KVCH; ++ch) s += ksp[(h * KVCH + ch) * 128 + c];
        ksum[h * 128 + c] = s;
    }
    __syncthreads();
    const float* wr = w + (long)t * DH;
    float m = 0.f;
    for (int d = 0; d < 128; ++d) m += kvrow[d] * wr[d];
    M[((long)(h * DH + c)) * DH + t] = m;
}

// ---------------- linear apply (writes d_out) ----------------
__global__ __launch_bounds__(256) void k_linear(const float* __restrict__ q,
                                                const float* __restrict__ M,
                                                const float* __restrict__ ksum,
                                                const float* __restrict__ bproj,
                                                float* __restrict__ out)
{
    __shared__ float fq[16][132];
    __shared__ float den[16];
    const int lb = blockIdx.x, h = blockIdx.y, t = threadIdx.x;
    const int l0 = lb * 16;
    {
        const int r = t >> 4, c0 = (t & 15) * 8;
        const float4* src = (const float4*)(q + ((long)((l0 + r) * NH + h)) * DH + c0);
        float4 a = src[0], b = src[1];
        float* dst = &fq[r][c0];
        dst[0] = a.x; dst[1] = a.y; dst[2] = a.z; dst[3] = a.w;
        dst[4] = b.x; dst[5] = b.y; dst[6] = b.z; dst[7] = b.w;
    }
    __syncthreads();
    {   // softmax + den: 16 threads per row
        const int row = t >> 4, sl = t & 15;
        float* fr = &fq[row][sl * 8];
        float mx = -__builtin_inff();
#pragma unroll
        for (int c = 0; c < 8; ++c) mx = fmaxf(mx, fr[c]);
        mx = fmaxf(mx, __shfl_xor(mx, 1));
        mx = fmaxf(mx, __shfl_xor(mx, 2));
        mx = fmaxf(mx, __shfl_xor(mx, 4));
        mx = fmaxf(mx, __shfl_xor(mx, 8));
        float sm = 0.f;
#pragma unroll
        for (int c = 0; c < 8; ++c) { float e = __expf(fr[c] - mx); fr[c] = e; sm += e; }
        sm += __shfl_xor(sm, 1);
        sm += __shfl_xor(sm, 2);
        sm += __shfl_xor(sm, 4);
        sm += __shfl_xor(sm, 8);
        float inv = 1.f / sm;
        const float* ks = ksum + h * DH + sl * 8;
        float dd = 0.f;
#pragma unroll
        for (int c = 0; c < 8; ++c) { float v2 = fr[c] * inv; fr[c] = v2; dd += v2 * ks[c]; }
        dd += __shfl_xor(dd, 1);
        dd += __shfl_xor(dd, 2);
        dd += __shfl_xor(dd, 4);
        dd += __shfl_xor(dd, 8);
        if (sl == 0) den[row] = 1e-5f + dd;
    }
    __syncthreads();
    const int e = t & 127, rg = t >> 7;
    float acc[8] = {0.f, 0.f, 0.f, 0.f, 0.f, 0.f, 0.f, 0.f};
    const float* Mh = M + (long)h * DH * DH + e;
    for (int c0 = 0; c0 < 128; c0 += 4) {
        const float m0 = Mh[(long)(c0 + 0) * DH];
        const float m1 = Mh[(long)(c0 + 1) * DH];
        const float m2 = Mh[(long)(c0 + 2) * DH];
        const float m3 = Mh[(long)(c0 + 3) * DH];
#pragma unroll
        for (int rr = 0; rr < 8; ++rr) {
            float4 f = *(const float4*)&fq[rg * 8 + rr][c0];
            acc[rr] += f.x * m0 + f.y * m1 + f.z * m2 + f.w * m3;
        }
    }
    const float b = bproj[e];
#pragma unroll
    for (int rr = 0; rr < 8; ++rr) {
        const int l = l0 + rg * 8 + rr;
        out[((long)(l * NH + h)) * DH + e] = acc[rr] / den[rg * 8 + rr] + b;
    }
}

// ---------------- sparse flash attention: 4 waves, static-max, cross-block split-K ----------------
// grid (qb, h, kc): block computes partial O,l over topk[kc*16 .. kc*16+15] for 128 Q rows.
// Static max: scores ~N(0,1) after scale -> exp(s) safe in fp32/bf16; no running max,
// no alpha rescale, no in-loop shuffles. Merge = simple sums (k_merge).
#define SM_K    0
#define SM_V    17408
#define SM_P    35840
#define SM_LUT  54272
#define SM_SZ   54336
__global__ __launch_bounds__(256, 2) void k_sparse(const float* __restrict__ q,
                                                   const __bf16* __restrict__ kb16,
                                                   const __bf16* __restrict__ vt16,
                                                   const int* __restrict__ lut,
                                                   float* __restrict__ Osp,
                                                   float* __restrict__ lsp)
{
    __shared__ __align__(16) char smem[SM_SZ];
    __bf16* Kl = (__bf16*)(smem + SM_K);    // [64][136]
    __bf16* Vl = (__bf16*)(smem + SM_V);    // [128][72]
    int* luts  = (int*)(smem + SM_LUT);

    const int qb = blockIdx.x, h = blockIdx.y, kc = blockIdx.z;
    const int t = threadIdx.x;
    const int w = t >> 6;
    const int lane = t & 63;
    const int l16 = lane & 15;
    const int quad = lane >> 4;

    if (t < 16) luts[t] = lut[(h * NQB + qb) * TOPK + kc * 16 + t];

    // Q fragments (A-layout) for rows qb*128 + w*32 + mt*16 + l16
    bf16x8 qf[2][4];
#pragma unroll
    for (int mt = 0; mt < 2; ++mt) {
        const int gl = qb * 128 + w * 32 + mt * 16 + l16;
        const float* qrow = q + ((long)(gl * NH + h)) * DH;
#pragma unroll
        for (int ks = 0; ks < 4; ++ks) {
            const float4* s2 = (const float4*)(qrow + ks * 32 + quad * 8);
            float4 a = s2[0], b = s2[1];
            bf16x8 f;
            f[0] = (__bf16)a.x; f[1] = (__bf16)a.y; f[2] = (__bf16)a.z; f[3] = (__bf16)a.w;
            f[4] = (__bf16)b.x; f[5] = (__bf16)b.y; f[6] = (__bf16)b.z; f[7] = (__bf16)b.w;
            qf[mt][ks] = f;
        }
    }

    const floatx4 vzero = {0.f, 0.f, 0.f, 0.f};
    floatx4 o_acc[2][8];
#pragma unroll
    for (int mt = 0; mt < 2; ++mt)
#pragma unroll
        for (int nt = 0; nt < 8; ++nt) o_acc[mt][nt] = vzero;
    float lsum[2][4];
#pragma unroll
    for (int mt = 0; mt < 2; ++mt)
#pragma unroll
        for (int r = 0; r < 4; ++r) lsum[mt][r] = 0.f;

    const float scale = 0.08838834764831845f;  // 1/sqrt(128)
    const __bf16* kbh = kb16 + (long)h * L_SEQ * DH;
    const __bf16* vth = vt16 + (long)h * DH * L_SEQ;
    // 256 threads stage 1024 K slots + 1024 V slots: 4 each
    int kr[4], kc8[4], vr[4], vc8[4];
#pragma unroll
    for (int j = 0; j < 4; ++j) {
        const int si = t + j * 256;
        kr[j] = si >> 4; kc8[j] = si & 15;   // K tile [64][128]
        vr[j] = si >> 3; vc8[j] = si & 7;    // V tile [128][64]
    }
    __bf16* Pw = (__bf16*)(smem + SM_P) + w * (32 * 72);

    __syncthreads();   // luts ready

    bf16x8 pk[4], pv[4];
    {
        const int b0 = luts[0];
#pragma unroll
        for (int j = 0; j < 4; ++j) {
            pk[j] = *(const bf16x8*)(kbh + ((long)(b0 * 64 + kr[j])) * DH + kc8[j] * 8);
            pv[j] = *(const bf16x8*)(vth + (long)vr[j] * L_SEQ + b0 * 64 + vc8[j] * 8);
        }
    }

    for (int it = 0; it < 16; ++it) {
#pragma unroll
        for (int j = 0; j < 4; ++j) {
            *(bf16x8*)(Kl + kr[j] * 136 + kc8[j] * 8) = pk[j];
            *(bf16x8*)(Vl + vr[j] * 72 + vc8[j] * 8)  = pv[j];
        }
        __syncthreads();   // tiles ready
        if (it < 15) {
            const int b0 = luts[it + 1];
#pragma unroll
            for (int j = 0; j < 4; ++j) {
                pk[j] = *(const bf16x8*)(kbh + ((long)(b0 * 64 + kr[j])) * DH + kc8[j] * 8);
                pv[j] = *(const bf16x8*)(vth + (long)vr[j] * L_SEQ + b0 * 64 + vc8[j] * 8);
            }
        }

        // S = Q @ K^T (32 rows x 64 keys per wave)
        floatx4 sfr[2][4];
#pragma unroll
        for (int mt = 0; mt < 2; ++mt)
#pragma unroll
            for (int nt = 0; nt < 4; ++nt) sfr[mt][nt] = vzero;
#pragma unroll
        for (int ks = 0; ks < 4; ++ks) {
            bf16x8 bf[4];
#pragma unroll
            for (int nt = 0; nt < 4; ++nt)
                bf[nt] = *(const bf16x8*)(Kl + (nt * 16 + l16) * 136 + ks * 32 + quad * 8);
#pragma unroll
            for (int mt = 0; mt < 2; ++mt)
#pragma unroll
                for (int nt = 0; nt < 4; ++nt)
                    sfr[mt][nt] = __builtin_amdgcn_mfma_f32_16x16x32_bf16(qf[mt][ks], bf[nt], sfr[mt][nt], 0, 0, 0);
        }

        // static-max softmax: p = exp(s*scale); accumulate per-lane row-sum partials
#pragma unroll
        for (int mt = 0; mt < 2; ++mt) {
#pragma unroll
            for (int r = 0; r < 4; ++r) {
                float p0 = __expf(sfr[mt][0][r] * scale);
                float p1 = __expf(sfr[mt][1][r] * scale);
                float p2 = __expf(sfr[mt][2][r] * scale);
                float p3 = __expf(sfr[mt][3][r] * scale);
                lsum[mt][r] += (p0 + p1) + (p2 + p3);
                __bf16* pb = Pw + (mt * 16 + quad * 4 + r) * 72 + l16;
                pb[0]  = (__bf16)p0;
                pb[16] = (__bf16)p1;
                pb[32] = (__bf16)p2;
                pb[48] = (__bf16)p3;
            }
        }

        // O += P @ V (P round-trip is wave-local)
#pragma unroll
        for (int ks2 = 0; ks2 < 2; ++ks2) {
            bf16x8 af[2];
#pragma unroll
            for (int mt = 0; mt < 2; ++mt)
                af[mt] = *(const bf16x8*)(Pw + (mt * 16 + l16) * 72 + ks2 * 32 + quad * 8);
#pragma unroll
            for (int nt = 0; nt < 8; ++nt) {
                bf16x8 bv = *(const bf16x8*)(Vl + (nt * 16 + l16) * 72 + ks2 * 32 + quad * 8);
#pragma unroll
                for (int mt = 0; mt < 2; ++mt)
                    o_acc[mt][nt] = __builtin_amdgcn_mfma_f32_16x16x32_bf16(af[mt], bv, o_acc[mt][nt], 0, 0, 0);
            }
        }
        __syncthreads();   // all waves done reading tiles
    }

    // epilogue: one shuffle-reduce of row sums; write partials
    const long pbase = (((long)(kc * NH + h) * NQB + qb)) * 128;
#pragma unroll
    for (int mt = 0; mt < 2; ++mt) {
#pragma unroll
        for (int r = 0; r < 4; ++r) {
            float ls = lsum[mt][r];
            ls += __shfl_xor(ls, 1);
            ls += __shfl_xor(ls, 2);
            ls += __shfl_xor(ls, 4);
            ls += __shfl_xor(ls, 8);
            const int row = w * 32 + mt * 16 + quad * 4 + r;
            if (l16 == 0) lsp[pbase + row] = ls;
            float* od = Osp + (pbase + row) * 128;
#pragma unroll
            for (int nt = 0; nt < 8; ++nt)
                od[nt * 16 + l16] = o_acc[mt][nt][r];
        }
    }
}

// ---------------- merge split-K partials into out (out already holds linear part) ----------------
__global__ __launch_bounds__(256) void k_merge(const float* __restrict__ Osp,
                                               const float* __restrict__ lsp,
                                               float* __restrict__ out)
{
    const int qb = blockIdx.x, h = blockIdx.y, t = threadIdx.x;
    const int row = t >> 1, e0 = (t & 1) * 64;
    const long p0 = (((long)(0 * NH + h) * NQB + qb)) * 128 + row;
    const long p1 = (((long)(1 * NH + h) * NQB + qb)) * 128 + row;
    const float inv = 1.f / (lsp[p0] + lsp[p1]);
    const float4* O0 = (const float4*)(Osp + p0 * 128 + e0);
    const float4* O1 = (const float4*)(Osp + p1 * 128 + e0);
    float4* op = (float4*)(out + ((long)((qb * 128 + row) * NH + h)) * DH + e0);
#pragma unroll
    for (int j = 0; j < 16; ++j) {
        float4 a = O0[j], b = O1[j], c = op[j];
        float4 rslt;
        rslt.x = c.x + (a.x + b.x) * inv;
        rslt.y = c.y + (a.y + b.y) * inv;
        rslt.z = c.z + (a.z + b.z) * inv;
        rslt.w = c.w + (a.w + b.w) * inv;
        op[j] = rslt;
    }
}

extern "C" void kernel_launch(void* const* d_in, const int* in_sizes, int n_in,
                              void* d_out, int out_size, void* d_ws, size_t ws_size,
                              hipStream_t stream)
{
    const float* q = (const float*)d_in[0];
    const float* k = (const float*)d_in[1];
    const float* v = (const float*)d_in[2];
    const float* w = (const float*)d_in[3];
    const float* b = (const float*)d_in[4];
    float* out = (float*)d_out;
    char* ws = (char*)d_ws;

    // workspace (~49.2 MB). kvp aliases the first half of Osp: kvp is dead
    // after k_reduce_m, Osp written only by k_sparse (later).
    __bf16* kb16 = (__bf16*)(ws + 0);          //  8,388,608  K bf16 [h][l][d]
    __bf16* vt16 = (__bf16*)(ws + 8388608);    //  8,388,608  V bf16 [h][d][l]
    float*  Osp  = (float*)(ws + 16777216);    // 33,554,432  sparse O partials [kc][h][qb][row][e]
    float*  kvp  = (float*)(ws + 16777216);    // 16,777,216  (alias) kv partials
    float*  lsp  = (float*)(ws + 50331648);    //    262,144  sparse l partials
    float*  pks  = (float*)(ws + 50593792);    //    262,144
    int*    lut  = (int*)  (ws + 50855936);    //     32,768
    float*  ksp  = (float*)(ws + 50888704);    //    131,072
    float*  ksum = (float*)(ws + 51019776);    //      4,096
    float*  M    = (float*)(ws + 51023872);    //    524,288

    k_prep_kv <<<dim3(64, 8),    dim3(256), 0, stream>>>(k, v, kb16, vt16, pks);
    k_route   <<<dim3(32, 8),    dim3(256), 0, stream>>>(q, pks, lut);
    k_kvpart  <<<dim3(KVCH, 8),  dim3(256), 0, stream>>>(k, v, kvp, ksp);
    k_reduce_m<<<dim3(128, 8),   dim3(128), 0, stream>>>(kvp, ksp, w, M, ksum);
    k_linear  <<<dim3(256, 8),   dim3(256), 0, stream>>>(q, M, ksum, b, out);     // writes d_out
    k_sparse  <<<dim3(32, 8, 2), dim3(256), 0, stream>>>(q, kb16, vt16, lut, Osp, lsp);
    k_merge   <<<dim3(32, 8),    dim3(256), 0, stream>>>(Osp, lsp, out);          // out += sparse
}

// Round 6
// 240.073 us; speedup vs baseline: 2.0322x; 1.1150x over previous
//
#include <hip/hip_runtime.h>
#include <hip/hip_bf16.h>

#define L_SEQ 4096
#define NH 8
#define DH 128
#define NQB 32
#define NKB 64
#define TOPK 32
#define KVCH 32   // kv partial chunks per head

typedef __bf16 bf16x8 __attribute__((ext_vector_type(8)));
typedef float floatx4 __attribute__((ext_vector_type(4)));

static_assert(sizeof(bf16x8) == 16, "bf16x8 must be 16B");

// ---------------- fused: K->bf16 [h][l][d]; V->bf16 transposed [h][d][l]; pks ----------------
__global__ __launch_bounds__(256) void k_prep_kv(const float* __restrict__ kin,
                                                 const float* __restrict__ vin,
                                                 __bf16* __restrict__ kb,
                                                 __bf16* __restrict__ vt,
                                                 float* __restrict__ pks)
{
    __shared__ float kt[64][129];
    __shared__ float vtile[64][129];
    const int lb = blockIdx.x, h = blockIdx.y, t = threadIdx.x;
    {
        const int r = t >> 2, seg = (t & 3) * 32;
        const float* ks = kin + ((long)((lb * 64 + r) * NH + h)) * DH + seg;
        const float* vs = vin + ((long)((lb * 64 + r) * NH + h)) * DH + seg;
        float frK[32];
#pragma unroll
        for (int j = 0; j < 8; ++j) {
            float4 a = ((const float4*)ks)[j];
            float4 b = ((const float4*)vs)[j];
            float* kd = &kt[r][seg + 4 * j];
            float* vd = &vtile[r][seg + 4 * j];
            kd[0] = a.x; kd[1] = a.y; kd[2] = a.z; kd[3] = a.w;
            vd[0] = b.x; vd[1] = b.y; vd[2] = b.z; vd[3] = b.w;
            frK[4 * j] = a.x; frK[4 * j + 1] = a.y; frK[4 * j + 2] = a.z; frK[4 * j + 3] = a.w;
        }
        bf16x8* kdst = (bf16x8*)(kb + ((long)(h * L_SEQ + lb * 64 + r)) * DH + seg);
#pragma unroll
        for (int g = 0; g < 4; ++g) {
            bf16x8 o;
#pragma unroll
            for (int e = 0; e < 8; ++e) o[e] = (__bf16)frK[g * 8 + e];
            kdst[g] = o;
        }
    }
    __syncthreads();
    if (t < 128) {   // K block column-sums -> pks
        float s = 0.f;
#pragma unroll 8
        for (int rr = 0; rr < 64; ++rr) s += kt[rr][t];
        pks[((long)(h * NKB + lb)) * DH + t] = s;
    }
    {   // V transpose -> vt16 [h][d][l]
        const int d = t >> 1, lh2 = (t & 1) * 32;
        bf16x8 ov[4];
#pragma unroll
        for (int i = 0; i < 32; ++i) ov[i >> 3][i & 7] = (__bf16)vtile[lh2 + i][d];
        bf16x8* dst = (bf16x8*)(vt + ((long)(h * DH + d)) * L_SEQ + lb * 64 + lh2);
#pragma unroll
        for (int j = 0; j < 4; ++j) dst[j] = ov[j];
    }
}

// ---------------- routing (fused Q-pool): rank-based top-32 ----------------
__global__ __launch_bounds__(256) void k_route(const float* __restrict__ q,
                                               const float* __restrict__ pks,
                                               int* __restrict__ lut)
{
    __shared__ float qv[128];
    __shared__ float qv2[128];
    __shared__ float sc[64];
    const int qi = blockIdx.x, h = blockIdx.y, t = threadIdx.x;
    {   // pooled q: 2 threads per column, 64 rows each
        const int d = t & 127, half = t >> 7;
        float acc = 0.f;
        const int r0 = half * 64;
#pragma unroll 4
        for (int r = 0; r < 64; ++r)
            acc += q[((long)((qi * 128 + r0 + r) * NH + h)) * DH + d];
        if (half == 0) qv[d] = acc; else qv2[d] = acc;
    }
    __syncthreads();
    if (t < 128) qv[t] += qv2[t];
    __syncthreads();
    if (t < 64) {
        const float4* pr = (const float4*)(pks + ((long)(h * NKB + t)) * DH);
        const float4* qp = (const float4*)qv;
        float s = 0.f;
#pragma unroll 8
        for (int d4 = 0; d4 < 32; ++d4) {
            float4 a = qp[d4], b = pr[d4];
            s += a.x * b.x + a.y * b.y + a.z * b.z + a.w * b.w;
        }
        sc[t] = s;
    }
    __syncthreads();
    if (t < 64) {
        const float s = sc[t];
        int rank = 0;
        for (int j2 = 0; j2 < 64; ++j2) {
            float o = sc[j2];
            rank += (o > s) || (o == s && j2 < t);
        }
        if (rank < TOPK) lut[(h * NQB + qi) * TOPK + rank] = t;
    }
}

// ---------------- kv partials (no atomics): 256 blocks, 128 rows each ----------------
__global__ __launch_bounds__(256) void k_kvpart(const float* __restrict__ kin,
                                                const float* __restrict__ vin,
                                                float* __restrict__ kvp,
                                                float* __restrict__ ksp)
{
    __shared__ float fk[64][132];
    __shared__ float vv[64][132];
    const int ch = blockIdx.x, h = blockIdx.y, t = threadIdx.x;
    const int ci = t & 15, di = t >> 4;
    const int lr = t >> 2, cs = (t & 3) * 32;
    float acc[8][8];
#pragma unroll
    for (int i = 0; i < 8; ++i)
#pragma unroll
        for (int j = 0; j < 8; ++j) acc[i][j] = 0.f;
    float ks8[8] = {0.f, 0.f, 0.f, 0.f, 0.f, 0.f, 0.f, 0.f};

    for (int sub = 0; sub < 2; ++sub) {
        const int l0 = ch * 128 + sub * 64;
        __syncthreads();
        {
            const float* ks = kin + ((long)((l0 + lr) * NH + h)) * DH + cs;
            const float* vs = vin + ((long)((l0 + lr) * NH + h)) * DH + cs;
#pragma unroll
            for (int j = 0; j < 8; ++j) {
                float4 a = ((const float4*)ks)[j];
                float4 b = ((const float4*)vs)[j];
                float* kd = &fk[lr][cs + 4 * j];
                float* vd = &vv[lr][cs + 4 * j];
                kd[0] = a.x; kd[1] = a.y; kd[2] = a.z; kd[3] = a.w;
                vd[0] = b.x; vd[1] = b.y; vd[2] = b.z; vd[3] = b.w;
            }
        }
        __syncthreads();
        {   // softmax: 4 threads per row
            const int row = t >> 2, cs2 = (t & 3) * 32;
            float mx = -__builtin_inff();
#pragma unroll 8
            for (int c = 0; c < 32; ++c) mx = fmaxf(mx, fk[row][cs2 + c]);
            mx = fmaxf(mx, __shfl_xor(mx, 1));
            mx = fmaxf(mx, __shfl_xor(mx, 2));
            float sm = 0.f;
#pragma unroll 8
            for (int c = 0; c < 32; ++c) { float e = __expf(fk[row][cs2 + c] - mx); fk[row][cs2 + c] = e; sm += e; }
            sm += __shfl_xor(sm, 1);
            sm += __shfl_xor(sm, 2);
            float inv = 1.f / sm;
#pragma unroll 8
            for (int c = 0; c < 32; ++c) fk[row][cs2 + c] *= inv;
        }
        __syncthreads();
        for (int l = 0; l < 64; ++l) {
            float4 a0 = *(const float4*)&fk[l][ci * 8];
            float4 a1 = *(const float4*)&fk[l][ci * 8 + 4];
            float4 b0 = *(const float4*)&vv[l][di * 8];
            float4 b1 = *(const float4*)&vv[l][di * 8 + 4];
            float av[8] = {a0.x, a0.y, a0.z, a0.w, a1.x, a1.y, a1.z, a1.w};
            float bv[8] = {b0.x, b0.y, b0.z, b0.w, b1.x, b1.y, b1.z, b1.w};
#pragma unroll
            for (int i = 0; i < 8; ++i)
#pragma unroll
                for (int j = 0; j < 8; ++j) acc[i][j] += av[i] * bv[j];
            if (di == 0) {
#pragma unroll
                for (int i = 0; i < 8; ++i) ks8[i] += av[i];
            }
        }
    }
    float* dst = kvp + (((long)(h * KVCH + ch) * 128) + ci * 8) * 128 + di * 8;
#pragma unroll
    for (int i = 0; i < 8; ++i) {
        float4 w0 = {acc[i][0], acc[i][1], acc[i][2], acc[i][3]};
        float4 w1 = {acc[i][4], acc[i][5], acc[i][6], acc[i][7]};
        ((float4*)(dst + (long)i * 128))[0] = w0;
        ((float4*)(dst + (long)i * 128))[1] = w1;
    }
    if (di == 0) {
        float* kd2 = ksp + (h * KVCH + ch) * 128 + ci * 8;
#pragma unroll
        for (int i = 0; i < 8; ++i) kd2[i] = ks8[i];
    }
}

// ---------------- reduce partials; M = kv @ W^T via in-LDS W transpose (coalesced) ----------------
// R5's version read w[e*128+d] per-lane-row = 64 lines/instruction. Now: transpose W
// into LDS once per block (conflict-free (t+e)%32 banking), read wt[d][t] coalesced.
__global__ __launch_bounds__(128) void k_reduce_m(const float* __restrict__ kvp,
                                                  const float* __restrict__ ksp,
                                                  const float* __restrict__ w,
                                                  float* __restrict__ M,
                                                  float* __restrict__ ksum)
{
    __shared__ float wt[128][129];   // [d][e]
    __shared__ float kvr[4][128];
    __shared__ float shks[4][32];
    const int cb = blockIdx.x, h = blockIdx.y, t = threadIdx.x;
    const int c0 = cb * 4;
    {   // W transpose: coalesced loads, conflict-free LDS writes
#pragma unroll 8
        for (int e = 0; e < 128; ++e) wt[t][e] = w[(long)e * DH + t];
    }
    {   // reduce kv partials for 4 c-rows
#pragma unroll
        for (int r = 0; r < 4; ++r) {
            float acc = 0.f;
            for (int ch = 0; ch < KVCH; ++ch)
                acc += kvp[(((long)(h * KVCH + ch) * 128) + c0 + r) * 128 + t];
            kvr[r][t] = acc;
        }
    }
    if (t < 128) {   // ksum partial stage
        const int r = t >> 5, ch = t & 31;
        shks[r][ch] = ksp[(h * KVCH + ch) * 128 + c0 + r];
    }
    __syncthreads();
    if (t < 4) {
        float s = 0.f;
#pragma unroll
        for (int ch = 0; ch < 32; ++ch) s += shks[t][ch];
        ksum[h * 128 + c0 + t] = s;
    }
    float m[4] = {0.f, 0.f, 0.f, 0.f};
#pragma unroll 4
    for (int d = 0; d < 128; ++d) {
        const float wv = wt[d][t];
#pragma unroll
        for (int r = 0; r < 4; ++r) m[r] += kvr[r][d] * wv;
    }
#pragma unroll
    for (int r = 0; r < 4; ++r)
        M[((long)(h * DH + c0 + r)) * DH + t] = m[r];
}

// ---------------- linear apply + sparse merge (writes d_out, runs LAST) ----------------
__global__ __launch_bounds__(256) void k_linear(const float* __restrict__ q,
                                                const float* __restrict__ M,
                                                const float* __restrict__ ksum,
                                                const float* __restrict__ bproj,
                                                const float* __restrict__ Osp,
                                                const float* __restrict__ lsp,
                                                float* __restrict__ out)
{
    __shared__ float fq[16][132];
    __shared__ float den[16];
    __shared__ float dsp[16];
    const int lb = blockIdx.x, h = blockIdx.y, t = threadIdx.x;
    const int l0 = lb * 16;
    {
        const int r = t >> 4, c0 = (t & 15) * 8;
        const float4* src = (const float4*)(q + ((long)((l0 + r) * NH + h)) * DH + c0);
        float4 a = src[0], b = src[1];
        float* dst = &fq[r][c0];
        dst[0] = a.x; dst[1] = a.y; dst[2] = a.z; dst[3] = a.w;
        dst[4] = b.x; dst[5] = b.y; dst[6] = b.z; dst[7] = b.w;
    }
    if (t < 16) {   // sparse denominators (sum of the two split-K partial sums)
        const int l = l0 + t, qb = l >> 7, rr = l & 127;
        const long p0 = ((long)(h * NQB + qb)) * 128 + rr;
        const long p1 = ((long)((NH + h) * NQB + qb)) * 128 + rr;
        dsp[t] = 1.f / (lsp[p0] + lsp[p1]);
    }
    __syncthreads();
    {   // softmax + den: 16 threads per row
        const int row = t >> 4, sl = t & 15;
        float* fr = &fq[row][sl * 8];
        float mx = -__builtin_inff();
#pragma unroll
        for (int c = 0; c < 8; ++c) mx = fmaxf(mx, fr[c]);
        mx = fmaxf(mx, __shfl_xor(mx, 1));
        mx = fmaxf(mx, __shfl_xor(mx, 2));
        mx = fmaxf(mx, __shfl_xor(mx, 4));
        mx = fmaxf(mx, __shfl_xor(mx, 8));
        float sm = 0.f;
#pragma unroll
        for (int c = 0; c < 8; ++c) { float e = __expf(fr[c] - mx); fr[c] = e; sm += e; }
        sm += __shfl_xor(sm, 1);
        sm += __shfl_xor(sm, 2);
        sm += __shfl_xor(sm, 4);
        sm += __shfl_xor(sm, 8);
        float inv = 1.f / sm;
        const float* ks = ksum + h * DH + sl * 8;
        float dd = 0.f;
#pragma unroll
        for (int c = 0; c < 8; ++c) { float v2 = fr[c] * inv; fr[c] = v2; dd += v2 * ks[c]; }
        dd += __shfl_xor(dd, 1);
        dd += __shfl_xor(dd, 2);
        dd += __shfl_xor(dd, 4);
        dd += __shfl_xor(dd, 8);
        if (sl == 0) den[row] = 1e-5f + dd;
    }
    __syncthreads();
    const int e = t & 127, rg = t >> 7;
    float acc[8] = {0.f, 0.f, 0.f, 0.f, 0.f, 0.f, 0.f, 0.f};
    const float* Mh = M + (long)h * DH * DH + e;
    for (int c0 = 0; c0 < 128; c0 += 4) {
        const float m0 = Mh[(long)(c0 + 0) * DH];
        const float m1 = Mh[(long)(c0 + 1) * DH];
        const float m2 = Mh[(long)(c0 + 2) * DH];
        const float m3 = Mh[(long)(c0 + 3) * DH];
#pragma unroll
        for (int rr = 0; rr < 8; ++rr) {
            float4 f = *(const float4*)&fq[rg * 8 + rr][c0];
            acc[rr] += f.x * m0 + f.y * m1 + f.z * m2 + f.w * m3;
        }
    }
    const float b = bproj[e];
    const int qb = l0 >> 7, rrb = l0 & 127;   // 16-row chunk never straddles a 128-row qb
    const long p0 = ((long)(h * NQB + qb)) * 128 + rrb;
    const long p1 = ((long)((NH + h) * NQB + qb)) * 128 + rrb;
#pragma unroll
    for (int rr = 0; rr < 8; ++rr) {
        const int row16 = rg * 8 + rr;
        const int l = l0 + row16;
        const float o0 = Osp[(p0 + row16) * 128 + e];
        const float o1 = Osp[(p1 + row16) * 128 + e];
        out[((long)(l * NH + h)) * DH + e] =
            acc[rr] / den[row16] + b + (o0 + o1) * dsp[row16];
    }
}

// ---------------- sparse flash attention: static-max, cross-block split-K, XCD-swizzled ----------------
// Flat grid 512; decode so all 32 qb-blocks of one (h,kc) pair share id%8 (one XCD):
// the pair's K/V working set (~2 MB) + a second pair = 4 MB = one XCD's L2.
#define SM_K    0
#define SM_V    17408
#define SM_P    35840
#define SM_LUT  54272
#define SM_SZ   54336
__global__ __launch_bounds__(256, 2) void k_sparse(const float* __restrict__ q,
                                                   const __bf16* __restrict__ kb16,
                                                   const __bf16* __restrict__ vt16,
                                                   const int* __restrict__ lut,
                                                   float* __restrict__ Osp,
                                                   float* __restrict__ lsp)
{
    __shared__ __align__(16) char smem[SM_SZ];
    __bf16* Kl = (__bf16*)(smem + SM_K);    // [64][136]
    __bf16* Vl = (__bf16*)(smem + SM_V);    // [128][72]
    int* luts  = (int*)(smem + SM_LUT);

    const int id = blockIdx.x;
    const int xcd = id & 7, slot = id >> 3;
    const int pair = xcd + 8 * (slot >> 5);   // 0..15
    const int qb = slot & 31;
    const int h = pair >> 1, kc = pair & 1;
    const int t = threadIdx.x;
    const int w = t >> 6;
    const int lane = t & 63;
    const int l16 = lane & 15;
    const int quad = lane >> 4;

    if (t < 16) luts[t] = lut[(h * NQB + qb) * TOPK + kc * 16 + t];

    // Q fragments (A-layout) for rows qb*128 + w*32 + mt*16 + l16
    bf16x8 qf[2][4];
#pragma unroll
    for (int mt = 0; mt < 2; ++mt) {
        const int gl = qb * 128 + w * 32 + mt * 16 + l16;
        const float* qrow = q + ((long)(gl * NH + h)) * DH;
#pragma unroll
        for (int ks = 0; ks < 4; ++ks) {
            const float4* s2 = (const float4*)(qrow + ks * 32 + quad * 8);
            float4 a = s2[0], b = s2[1];
            bf16x8 f;
            f[0] = (__bf16)a.x; f[1] = (__bf16)a.y; f[2] = (__bf16)a.z; f[3] = (__bf16)a.w;
            f[4] = (__bf16)b.x; f[5] = (__bf16)b.y; f[6] = (__bf16)b.z; f[7] = (__bf16)b.w;
            qf[mt][ks] = f;
        }
    }

    const floatx4 vzero = {0.f, 0.f, 0.f, 0.f};
    floatx4 o_acc[2][8];
#pragma unroll
    for (int mt = 0; mt < 2; ++mt)
#pragma unroll
        for (int nt = 0; nt < 8; ++nt) o_acc[mt][nt] = vzero;
    float lsum[2][4];
#pragma unroll
    for (int mt = 0; mt < 2; ++mt)
#pragma unroll
        for (int r = 0; r < 4; ++r) lsum[mt][r] = 0.f;

    const float scale = 0.08838834764831845f;  // 1/sqrt(128)
    const __bf16* kbh = kb16 + (long)h * L_SEQ * DH;
    const __bf16* vth = vt16 + (long)h * DH * L_SEQ;
    int kr[4], kc8[4], vr[4], vc8[4];
#pragma unroll
    for (int j = 0; j < 4; ++j) {
        const int si = t + j * 256;
        kr[j] = si >> 4; kc8[j] = si & 15;   // K tile [64][128]
        vr[j] = si >> 3; vc8[j] = si & 7;    // V tile [128][64]
    }
    __bf16* Pw = (__bf16*)(smem + SM_P) + w * (32 * 72);

    __syncthreads();   // luts ready

    bf16x8 pk[4], pv[4];
    {
        const int b0 = luts[0];
#pragma unroll
        for (int j = 0; j < 4; ++j) {
            pk[j] = *(const bf16x8*)(kbh + ((long)(b0 * 64 + kr[j])) * DH + kc8[j] * 8);
            pv[j] = *(const bf16x8*)(vth + (long)vr[j] * L_SEQ + b0 * 64 + vc8[j] * 8);
        }
    }

    for (int it = 0; it < 16; ++it) {
#pragma unroll
        for (int j = 0; j < 4; ++j) {
            *(bf16x8*)(Kl + kr[j] * 136 + kc8[j] * 8) = pk[j];
            *(bf16x8*)(Vl + vr[j] * 72 + vc8[j] * 8)  = pv[j];
        }
        __syncthreads();   // tiles ready
        if (it < 15) {
            const int b0 = luts[it + 1];
#pragma unroll
            for (int j = 0; j < 4; ++j) {
                pk[j] = *(const bf16x8*)(kbh + ((long)(b0 * 64 + kr[j])) * DH + kc8[j] * 8);
                pv[j] = *(const bf16x8*)(vth + (long)vr[j] * L_SEQ + b0 * 64 + vc8[j] * 8);
            }
        }

        // S = Q @ K^T (32 rows x 64 keys per wave)
        floatx4 sfr[2][4];
#pragma unroll
        for (int mt = 0; mt < 2; ++mt)
#pragma unroll
            for (int nt = 0; nt < 4; ++nt) sfr[mt][nt] = vzero;
#pragma unroll
        for (int ks = 0; ks < 4; ++ks) {
            bf16x8 bf[4];
#pragma unroll
            for (int nt = 0; nt < 4; ++nt)
                bf[nt] = *(const bf16x8*)(Kl + (nt * 16 + l16) * 136 + ks * 32 + quad * 8);
#pragma unroll
            for (int mt = 0; mt < 2; ++mt)
#pragma unroll
                for (int nt = 0; nt < 4; ++nt)
                    sfr[mt][nt] = __builtin_amdgcn_mfma_f32_16x16x32_bf16(qf[mt][ks], bf[nt], sfr[mt][nt], 0, 0, 0);
        }

        // static-max softmax: p = exp(s*scale); per-lane row-sum partials
#pragma unroll
        for (int mt = 0; mt < 2; ++mt) {
#pragma unroll
            for (int r = 0; r < 4; ++r) {
                float p0 = __expf(sfr[mt][0][r] * scale);
                float p1 = __expf(sfr[mt][1][r] * scale);
                float p2 = __expf(sfr[mt][2][r] * scale);
                float p3 = __expf(sfr[mt][3][r] * scale);
                lsum[mt][r] += (p0 + p1) + (p2 + p3);
                __bf16* pb = Pw + (mt * 16 + quad * 4 + r) * 72 + l16;
                pb[0]  = (__bf16)p0;
                pb[16] = (__bf16)p1;
                pb[32] = (__bf16)p2;
                pb[48] = (__bf16)p3;
            }
        }

        // O += P @ V (P round-trip is wave-local)
#pragma unroll
        for (int ks2 = 0; ks2 < 2; ++ks2) {
            bf16x8 af[2];
#pragma unroll
            for (int mt = 0; mt < 2; ++mt)
                af[mt] = *(const bf16x8*)(Pw + (mt * 16 + l16) * 72 + ks2 * 32 + quad * 8);
#pragma unroll
            for (int nt = 0; nt < 8; ++nt) {
                bf16x8 bv = *(const bf16x8*)(Vl + (nt * 16 + l16) * 72 + ks2 * 32 + quad * 8);
#pragma unroll
                for (int mt = 0; mt < 2; ++mt)
                    o_acc[mt][nt] = __builtin_amdgcn_mfma_f32_16x16x32_bf16(af[mt], bv, o_acc[mt][nt], 0, 0, 0);
            }
        }
        __syncthreads();   // all waves done reading tiles
    }

    // epilogue: one shuffle-reduce of row sums; write partials
    const long pbase = (((long)(kc * NH + h) * NQB + qb)) * 128;
#pragma unroll
    for (int mt = 0; mt < 2; ++mt) {
#pragma unroll
        for (int r = 0; r < 4; ++r) {
            float ls = lsum[mt][r];
            ls += __shfl_xor(ls, 1);
            ls += __shfl_xor(ls, 2);
            ls += __shfl_xor(ls, 4);
            ls += __shfl_xor(ls, 8);
            const int row = w * 32 + mt * 16 + quad * 4 + r;
            if (l16 == 0) lsp[pbase + row] = ls;
            float* od = Osp + (pbase + row) * 128;
#pragma unroll
            for (int nt = 0; nt < 8; ++nt)
                od[nt * 16 + l16] = o_acc[mt][nt][r];
        }
    }
}

extern "C" void kernel_launch(void* const* d_in, const int* in_sizes, int n_in,
                              void* d_out, int out_size, void* d_ws, size_t ws_size,
                              hipStream_t stream)
{
    const float* q = (const float*)d_in[0];
    const float* k = (const float*)d_in[1];
    const float* v = (const float*)d_in[2];
    const float* w = (const float*)d_in[3];
    const float* b = (const float*)d_in[4];
    float* out = (float*)d_out;
    char* ws = (char*)d_ws;

    // workspace (~49.2 MB). kvp aliases the first half of Osp: kvp dead after
    // k_reduce_m (dispatch 4); Osp written by k_sparse (dispatch 5). Serial stream.
    __bf16* kb16 = (__bf16*)(ws + 0);          //  8,388,608  K bf16 [h][l][d]
    __bf16* vt16 = (__bf16*)(ws + 8388608);    //  8,388,608  V bf16 [h][d][l]
    float*  Osp  = (float*)(ws + 16777216);    // 33,554,432  sparse O partials [kc][h][qb][row][e]
    float*  kvp  = (float*)(ws + 16777216);    // 16,777,216  (alias) kv partials
    float*  lsp  = (float*)(ws + 50331648);    //    262,144  sparse l partials
    float*  pks  = (float*)(ws + 50593792);    //    262,144
    int*    lut  = (int*)  (ws + 50855936);    //     32,768
    float*  ksp  = (float*)(ws + 50888704);    //    131,072
    float*  ksum = (float*)(ws + 51019776);    //      4,096
    float*  M    = (float*)(ws + 51023872);    //    524,288

    k_prep_kv <<<dim3(64, 8),   dim3(256), 0, stream>>>(k, v, kb16, vt16, pks);
    k_route   <<<dim3(32, 8),   dim3(256), 0, stream>>>(q, pks, lut);
    k_kvpart  <<<dim3(KVCH, 8), dim3(256), 0, stream>>>(k, v, kvp, ksp);
    k_reduce_m<<<dim3(32, 8),   dim3(128), 0, stream>>>(kvp, ksp, w, M, ksum);
    k_sparse  <<<dim3(512),     dim3(256), 0, stream>>>(q, kb16, vt16, lut, Osp, lsp);
    k_linear  <<<dim3(256, 8),  dim3(256), 0, stream>>>(q, M, ksum, b, Osp, lsp, out); // writes d_out
}

// Round 7
// 219.905 us; speedup vs baseline: 2.2186x; 1.0917x over previous
//
#include <hip/hip_runtime.h>
#include <hip/hip_bf16.h>

#define L_SEQ 4096
#define NH 8
#define DH 128
#define NQB 32
#define NKB 64
#define TOPK 32
#define KVCH 64   // kv partial chunks per head (64 rows each)

typedef __bf16 bf16x8 __attribute__((ext_vector_type(8)));
typedef __bf16 bf16x4 __attribute__((ext_vector_type(4)));
typedef float floatx4 __attribute__((ext_vector_type(4)));

static_assert(sizeof(bf16x8) == 16, "bf16x8 must be 16B");
static_assert(sizeof(bf16x4) == 8, "bf16x4 must be 8B");

// ---------------- fused: K->bf16 [h][l][d]; V->bf16 transposed [h][d][l]; pks ----------------
__global__ __launch_bounds__(256) void k_prep_kv(const float* __restrict__ kin,
                                                 const float* __restrict__ vin,
                                                 __bf16* __restrict__ kb,
                                                 __bf16* __restrict__ vt,
                                                 float* __restrict__ pks)
{
    __shared__ float kt[64][129];
    __shared__ float vtile[64][129];
    const int lb = blockIdx.x, h = blockIdx.y, t = threadIdx.x;
    {
        const int r = t >> 2, seg = (t & 3) * 32;
        const float* ks = kin + ((long)((lb * 64 + r) * NH + h)) * DH + seg;
        const float* vs = vin + ((long)((lb * 64 + r) * NH + h)) * DH + seg;
        float frK[32];
#pragma unroll
        for (int j = 0; j < 8; ++j) {
            float4 a = ((const float4*)ks)[j];
            float4 b = ((const float4*)vs)[j];
            float* kd = &kt[r][seg + 4 * j];
            float* vd = &vtile[r][seg + 4 * j];
            kd[0] = a.x; kd[1] = a.y; kd[2] = a.z; kd[3] = a.w;
            vd[0] = b.x; vd[1] = b.y; vd[2] = b.z; vd[3] = b.w;
            frK[4 * j] = a.x; frK[4 * j + 1] = a.y; frK[4 * j + 2] = a.z; frK[4 * j + 3] = a.w;
        }
        bf16x8* kdst = (bf16x8*)(kb + ((long)(h * L_SEQ + lb * 64 + r)) * DH + seg);
#pragma unroll
        for (int g = 0; g < 4; ++g) {
            bf16x8 o;
#pragma unroll
            for (int e = 0; e < 8; ++e) o[e] = (__bf16)frK[g * 8 + e];
            kdst[g] = o;
        }
    }
    __syncthreads();
    if (t < 128) {   // K block column-sums -> pks
        float s = 0.f;
#pragma unroll 8
        for (int rr = 0; rr < 64; ++rr) s += kt[rr][t];
        pks[((long)(h * NKB + lb)) * DH + t] = s;
    }
    {   // V transpose -> vt16 [h][d][l]
        const int d = t >> 1, lh2 = (t & 1) * 32;
        bf16x8 ov[4];
#pragma unroll
        for (int i = 0; i < 32; ++i) ov[i >> 3][i & 7] = (__bf16)vtile[lh2 + i][d];
        bf16x8* dst = (bf16x8*)(vt + ((long)(h * DH + d)) * L_SEQ + lb * 64 + lh2);
#pragma unroll
        for (int j = 0; j < 4; ++j) dst[j] = ov[j];
    }
}

// ---------------- routing (fused Q-pool): rank-based top-32 ----------------
__global__ __launch_bounds__(256) void k_route(const float* __restrict__ q,
                                               const float* __restrict__ pks,
                                               int* __restrict__ lut)
{
    __shared__ float qv[128];
    __shared__ float qv2[128];
    __shared__ float sc[64];
    const int qi = blockIdx.x, h = blockIdx.y, t = threadIdx.x;
    {
        const int d = t & 127, half = t >> 7;
        float acc = 0.f;
        const int r0 = half * 64;
#pragma unroll 4
        for (int r = 0; r < 64; ++r)
            acc += q[((long)((qi * 128 + r0 + r) * NH + h)) * DH + d];
        if (half == 0) qv[d] = acc; else qv2[d] = acc;
    }
    __syncthreads();
    if (t < 128) qv[t] += qv2[t];
    __syncthreads();
    if (t < 64) {
        const float4* pr = (const float4*)(pks + ((long)(h * NKB + t)) * DH);
        const float4* qp = (const float4*)qv;
        float s = 0.f;
#pragma unroll 8
        for (int d4 = 0; d4 < 32; ++d4) {
            float4 a = qp[d4], b = pr[d4];
            s += a.x * b.x + a.y * b.y + a.z * b.z + a.w * b.w;
        }
        sc[t] = s;
    }
    __syncthreads();
    if (t < 64) {
        const float s = sc[t];
        int rank = 0;
        for (int j2 = 0; j2 < 64; ++j2) {
            float o = sc[j2];
            rank += (o > s) || (o == s && j2 < t);
        }
        if (rank < TOPK) lut[(h * NQB + qi) * TOPK + rank] = t;
    }
}

// ---------------- kv partials: 512 blocks, 64 rows each, register softmax ----------------
__global__ __launch_bounds__(256) void k_kvpart(const float* __restrict__ kin,
                                                const float* __restrict__ vin,
                                                float* __restrict__ kvp,
                                                float* __restrict__ ksp)
{
    __shared__ float fk[64][132];
    __shared__ float vv[64][132];
    const int ch = blockIdx.x, h = blockIdx.y, t = threadIdx.x;
    const int l0 = ch * 64;
    const int lr = t >> 2, cs = (t & 3) * 32;
    {   // stage 64 rows of K and V (fp32)
        const float* ks = kin + ((long)((l0 + lr) * NH + h)) * DH + cs;
        const float* vs = vin + ((long)((l0 + lr) * NH + h)) * DH + cs;
#pragma unroll
        for (int j = 0; j < 8; ++j) {
            float4 a = ((const float4*)ks)[j];
            float4 b = ((const float4*)vs)[j];
            float* kd = &fk[lr][cs + 4 * j];
            float* vd = &vv[lr][cs + 4 * j];
            kd[0] = a.x; kd[1] = a.y; kd[2] = a.z; kd[3] = a.w;
            vd[0] = b.x; vd[1] = b.y; vd[2] = b.z; vd[3] = b.w;
        }
    }
    __syncthreads();
    {   // softmax: 4 threads/row, 32 cols each, held in registers (float4 LDS I/O)
        float vals[32];
        float* fr = &fk[lr][cs];
#pragma unroll
        for (int j = 0; j < 8; ++j) {
            float4 x = ((const float4*)fr)[j];
            vals[4*j] = x.x; vals[4*j+1] = x.y; vals[4*j+2] = x.z; vals[4*j+3] = x.w;
        }
        float mx = -__builtin_inff();
#pragma unroll
        for (int c = 0; c < 32; ++c) mx = fmaxf(mx, vals[c]);
        mx = fmaxf(mx, __shfl_xor(mx, 1));
        mx = fmaxf(mx, __shfl_xor(mx, 2));
        float sm = 0.f;
#pragma unroll
        for (int c = 0; c < 32; ++c) { vals[c] = __expf(vals[c] - mx); sm += vals[c]; }
        sm += __shfl_xor(sm, 1);
        sm += __shfl_xor(sm, 2);
        const float inv = 1.f / sm;
#pragma unroll
        for (int j = 0; j < 8; ++j) {
            float4 x = {vals[4*j] * inv, vals[4*j+1] * inv, vals[4*j+2] * inv, vals[4*j+3] * inv};
            ((float4*)fr)[j] = x;
        }
    }
    __syncthreads();
    const int ci = t & 15, di = t >> 4;
    float acc[8][8];
#pragma unroll
    for (int i = 0; i < 8; ++i)
#pragma unroll
        for (int j = 0; j < 8; ++j) acc[i][j] = 0.f;
    float ks8[8] = {0.f, 0.f, 0.f, 0.f, 0.f, 0.f, 0.f, 0.f};
    for (int l = 0; l < 64; ++l) {
        float4 a0 = *(const float4*)&fk[l][ci * 8];
        float4 a1 = *(const float4*)&fk[l][ci * 8 + 4];
        float4 b0 = *(const float4*)&vv[l][di * 8];
        float4 b1 = *(const float4*)&vv[l][di * 8 + 4];
        float av[8] = {a0.x, a0.y, a0.z, a0.w, a1.x, a1.y, a1.z, a1.w};
        float bv[8] = {b0.x, b0.y, b0.z, b0.w, b1.x, b1.y, b1.z, b1.w};
#pragma unroll
        for (int i = 0; i < 8; ++i)
#pragma unroll
            for (int j = 0; j < 8; ++j) acc[i][j] += av[i] * bv[j];
        if (di == 0) {
#pragma unroll
            for (int i = 0; i < 8; ++i) ks8[i] += av[i];
        }
    }
    float* dst = kvp + (((long)(h * KVCH + ch) * 128) + ci * 8) * 128 + di * 8;
#pragma unroll
    for (int i = 0; i < 8; ++i) {
        float4 w0 = {acc[i][0], acc[i][1], acc[i][2], acc[i][3]};
        float4 w1 = {acc[i][4], acc[i][5], acc[i][6], acc[i][7]};
        ((float4*)(dst + (long)i * 128))[0] = w0;
        ((float4*)(dst + (long)i * 128))[1] = w1;
    }
    if (di == 0) {
        float* kd2 = ksp + (h * KVCH + ch) * 128 + ci * 8;
#pragma unroll
        for (int i = 0; i < 8; ++i) kd2[i] = ks8[i];
    }
}

// ---------------- reduce partials; Mt[h][e][c] = (kv @ W^T)^T in bf16; ksum ----------------
__global__ __launch_bounds__(128) void k_reduce_m(const float* __restrict__ kvp,
                                                  const float* __restrict__ ksp,
                                                  const float* __restrict__ w,
                                                  __bf16* __restrict__ Mt,
                                                  float* __restrict__ ksum)
{
    __shared__ float wt[128][129];   // [d][e]
    __shared__ float kvr[4][128];
    __shared__ float shks[4][64];
    const int cb = blockIdx.x, h = blockIdx.y, t = threadIdx.x;
    const int c0 = cb * 4;
    {   // W transpose: coalesced loads, 2-way-free LDS writes
#pragma unroll 8
        for (int e = 0; e < 128; ++e) wt[t][e] = w[(long)e * DH + t];
    }
    {   // reduce kv partials for 4 c-rows
#pragma unroll
        for (int r = 0; r < 4; ++r) {
            float acc = 0.f;
            for (int ch = 0; ch < KVCH; ++ch)
                acc += kvp[(((long)(h * KVCH + ch) * 128) + c0 + r) * 128 + t];
            kvr[r][t] = acc;
        }
    }
    for (int i = t; i < 256; i += 128) {   // ksum partial stage
        const int r = i >> 6, ch = i & 63;
        shks[r][ch] = ksp[(h * KVCH + ch) * 128 + c0 + r];
    }
    __syncthreads();
    if (t < 4) {
        float s = 0.f;
#pragma unroll
        for (int ch = 0; ch < 64; ++ch) s += shks[t][ch];
        ksum[h * 128 + c0 + t] = s;
    }
    float m[4] = {0.f, 0.f, 0.f, 0.f};
#pragma unroll 4
    for (int d = 0; d < 128; ++d) {
        const float wv = wt[d][t];
#pragma unroll
        for (int r = 0; r < 4; ++r) m[r] += kvr[r][d] * wv;
    }
    // lane t owns Mt[e=t][c0..c0+3] -> one 8B store
    bf16x4 pk;
#pragma unroll
    for (int r = 0; r < 4; ++r) pk[r] = (__bf16)m[r];
    *(bf16x4*)(Mt + ((long)(h * 128 + t)) * 128 + c0) = pk;
}

// ---------------- linear apply (MFMA) + sparse merge: writes d_out, runs LAST ----------------
// out = (e @ M)/(eps*sm + e·ksum) + bias + (Osp0+Osp1)/(l0+l1),  e = raw exp(q - max)
// (normalization by sm cancels -> skip it). A = e (bf16, LDS), B = Mt[h][e][c] (bf16, global).
__global__ __launch_bounds__(256) void k_linear(const float* __restrict__ q,
                                                const __bf16* __restrict__ Mt,
                                                const float* __restrict__ ksum,
                                                const float* __restrict__ bproj,
                                                const float* __restrict__ Osp,
                                                const float* __restrict__ lsp,
                                                float* __restrict__ out)
{
    __shared__ __align__(16) __bf16 fq[128 * 136];   // raw exp, stride 136
    __shared__ float dinv[128];
    __shared__ float dsp[128];
    const int qb = blockIdx.x, h = blockIdx.y, t = threadIdx.x;
    const int l0 = qb * 128;

    {   // phase 1: per-row raw-exp + fused denominator; 2 threads/row
        const int row = t >> 1, half = t & 1;
        const float* qrow = q + ((long)((l0 + row) * NH + h)) * DH + half * 64;
        float vals[64];
#pragma unroll
        for (int j = 0; j < 16; ++j) {
            float4 x = ((const float4*)qrow)[j];
            vals[4*j] = x.x; vals[4*j+1] = x.y; vals[4*j+2] = x.z; vals[4*j+3] = x.w;
        }
        float mx = -__builtin_inff();
#pragma unroll
        for (int c = 0; c < 64; ++c) mx = fmaxf(mx, vals[c]);
        mx = fmaxf(mx, __shfl_xor(mx, 1));
        float sm = 0.f, dk = 0.f;
        const float* ks = ksum + h * DH + half * 64;
#pragma unroll
        for (int c = 0; c < 64; ++c) {
            float e = __expf(vals[c] - mx);
            vals[c] = e; sm += e; dk += e * ks[c];
        }
        __bf16* dst = fq + row * 136 + half * 64;
#pragma unroll
        for (int g = 0; g < 8; ++g) {
            bf16x8 o;
#pragma unroll
            for (int e2 = 0; e2 < 8; ++e2) o[e2] = (__bf16)vals[g * 8 + e2];
            *(bf16x8*)(dst + g * 8) = o;
        }
        sm += __shfl_xor(sm, 1);
        dk += __shfl_xor(dk, 1);
        if (half == 0) dinv[row] = 1.f / (1e-5f * sm + dk);
    }
    if (t < 128) {
        const long p0 = ((long)(h * NQB + qb)) * 128 + t;
        const long p1 = ((long)((NH + h) * NQB + qb)) * 128 + t;
        dsp[t] = 1.f / (lsp[p0] + lsp[p1]);
    }
    __syncthreads();

    // phase 2: MFMA  [128 rows x 128 e], wave w owns rows w*32..+32
    const int w = t >> 6, lane = t & 63, l16 = lane & 15, quad = lane >> 4;
    const __bf16* Bh = Mt + (long)h * DH * DH;
    const floatx4 vzero = {0.f, 0.f, 0.f, 0.f};
    floatx4 acc[2][8];
#pragma unroll
    for (int mt = 0; mt < 2; ++mt)
#pragma unroll
        for (int nt = 0; nt < 8; ++nt) acc[mt][nt] = vzero;
#pragma unroll
    for (int ksx = 0; ksx < 4; ++ksx) {
        bf16x8 af[2];
#pragma unroll
        for (int mt = 0; mt < 2; ++mt)
            af[mt] = *(const bf16x8*)(fq + (w * 32 + mt * 16 + l16) * 136 + ksx * 32 + quad * 8);
#pragma unroll
        for (int nt = 0; nt < 8; ++nt) {
            bf16x8 bf = *(const bf16x8*)(Bh + ((long)(nt * 16 + l16)) * DH + ksx * 32 + quad * 8);
#pragma unroll
            for (int mt = 0; mt < 2; ++mt)
                acc[mt][nt] = __builtin_amdgcn_mfma_f32_16x16x32_bf16(af[mt], bf, acc[mt][nt], 0, 0, 0);
        }
    }

    // epilogue: denom, bias, sparse merge
    float bias[8];
#pragma unroll
    for (int nt = 0; nt < 8; ++nt) bias[nt] = bproj[nt * 16 + l16];
    const float* O0b = Osp + (((long)(h * NQB + qb)) * 128) * 128;
    const float* O1b = Osp + (((long)((NH + h) * NQB + qb)) * 128) * 128;
#pragma unroll
    for (int mt = 0; mt < 2; ++mt) {
#pragma unroll
        for (int r = 0; r < 4; ++r) {
            const int row = w * 32 + mt * 16 + quad * 4 + r;
            const float di = dinv[row], ds = dsp[row];
            float* op = out + ((long)((l0 + row) * NH + h)) * DH;
            const float* o0 = O0b + (long)row * 128;
            const float* o1 = O1b + (long)row * 128;
#pragma unroll
            for (int nt = 0; nt < 8; ++nt) {
                const int e = nt * 16 + l16;
                op[e] = acc[mt][nt][r] * di + bias[nt] + (o0[e] + o1[e]) * ds;
            }
        }
    }
}

// ---------------- sparse flash attention: static-max, cross-block split-K, XCD-swizzled ----------------
#define SM_K    0
#define SM_V    17408
#define SM_P    35840
#define SM_LUT  54272
#define SM_SZ   54336
__global__ __launch_bounds__(256, 2) void k_sparse(const float* __restrict__ q,
                                                   const __bf16* __restrict__ kb16,
                                                   const __bf16* __restrict__ vt16,
                                                   const int* __restrict__ lut,
                                                   float* __restrict__ Osp,
                                                   float* __restrict__ lsp)
{
    __shared__ __align__(16) char smem[SM_SZ];
    __bf16* Kl = (__bf16*)(smem + SM_K);    // [64][136]
    __bf16* Vl = (__bf16*)(smem + SM_V);    // [128][72]
    int* luts  = (int*)(smem + SM_LUT);

    const int id = blockIdx.x;
    const int xcd = id & 7, slot = id >> 3;
    const int pair = xcd + 8 * (slot >> 5);   // 0..15
    const int qb = slot & 31;
    const int h = pair >> 1, kc = pair & 1;
    const int t = threadIdx.x;
    const int w = t >> 6;
    const int lane = t & 63;
    const int l16 = lane & 15;
    const int quad = lane >> 4;

    if (t < 16) luts[t] = lut[(h * NQB + qb) * TOPK + kc * 16 + t];

    bf16x8 qf[2][4];
#pragma unroll
    for (int mt = 0; mt < 2; ++mt) {
        const int gl = qb * 128 + w * 32 + mt * 16 + l16;
        const float* qrow = q + ((long)(gl * NH + h)) * DH;
#pragma unroll
        for (int ks = 0; ks < 4; ++ks) {
            const float4* s2 = (const float4*)(qrow + ks * 32 + quad * 8);
            float4 a = s2[0], b = s2[1];
            bf16x8 f;
            f[0] = (__bf16)a.x; f[1] = (__bf16)a.y; f[2] = (__bf16)a.z; f[3] = (__bf16)a.w;
            f[4] = (__bf16)b.x; f[5] = (__bf16)b.y; f[6] = (__bf16)b.z; f[7] = (__bf16)b.w;
            qf[mt][ks] = f;
        }
    }

    const floatx4 vzero = {0.f, 0.f, 0.f, 0.f};
    floatx4 o_acc[2][8];
#pragma unroll
    for (int mt = 0; mt < 2; ++mt)
#pragma unroll
        for (int nt = 0; nt < 8; ++nt) o_acc[mt][nt] = vzero;
    float lsum[2][4];
#pragma unroll
    for (int mt = 0; mt < 2; ++mt)
#pragma unroll
        for (int r = 0; r < 4; ++r) lsum[mt][r] = 0.f;

    const float scale = 0.08838834764831845f;
    const __bf16* kbh = kb16 + (long)h * L_SEQ * DH;
    const __bf16* vth = vt16 + (long)h * DH * L_SEQ;
    int kr[4], kc8[4], vr[4], vc8[4];
#pragma unroll
    for (int j = 0; j < 4; ++j) {
        const int si = t + j * 256;
        kr[j] = si >> 4; kc8[j] = si & 15;
        vr[j] = si >> 3; vc8[j] = si & 7;
    }
    __bf16* Pw = (__bf16*)(smem + SM_P) + w * (32 * 72);

    __syncthreads();

    bf16x8 pk[4], pv[4];
    {
        const int b0 = luts[0];
#pragma unroll
        for (int j = 0; j < 4; ++j) {
            pk[j] = *(const bf16x8*)(kbh + ((long)(b0 * 64 + kr[j])) * DH + kc8[j] * 8);
            pv[j] = *(const bf16x8*)(vth + (long)vr[j] * L_SEQ + b0 * 64 + vc8[j] * 8);
        }
    }

    for (int it = 0; it < 16; ++it) {
#pragma unroll
        for (int j = 0; j < 4; ++j) {
            *(bf16x8*)(Kl + kr[j] * 136 + kc8[j] * 8) = pk[j];
            *(bf16x8*)(Vl + vr[j] * 72 + vc8[j] * 8)  = pv[j];
        }
        __syncthreads();
        if (it < 15) {
            const int b0 = luts[it + 1];
#pragma unroll
            for (int j = 0; j < 4; ++j) {
                pk[j] = *(const bf16x8*)(kbh + ((long)(b0 * 64 + kr[j])) * DH + kc8[j] * 8);
                pv[j] = *(const bf16x8*)(vth + (long)vr[j] * L_SEQ + b0 * 64 + vc8[j] * 8);
            }
        }

        floatx4 sfr[2][4];
#pragma unroll
        for (int mt = 0; mt < 2; ++mt)
#pragma unroll
            for (int nt = 0; nt < 4; ++nt) sfr[mt][nt] = vzero;
#pragma unroll
        for (int ks = 0; ks < 4; ++ks) {
            bf16x8 bf[4];
#pragma unroll
            for (int nt = 0; nt < 4; ++nt)
                bf[nt] = *(const bf16x8*)(Kl + (nt * 16 + l16) * 136 + ks * 32 + quad * 8);
#pragma unroll
            for (int mt = 0; mt < 2; ++mt)
#pragma unroll
                for (int nt = 0; nt < 4; ++nt)
                    sfr[mt][nt] = __builtin_amdgcn_mfma_f32_16x16x32_bf16(qf[mt][ks], bf[nt], sfr[mt][nt], 0, 0, 0);
        }

#pragma unroll
        for (int mt = 0; mt < 2; ++mt) {
#pragma unroll
            for (int r = 0; r < 4; ++r) {
                float p0 = __expf(sfr[mt][0][r] * scale);
                float p1 = __expf(sfr[mt][1][r] * scale);
                float p2 = __expf(sfr[mt][2][r] * scale);
                float p3 = __expf(sfr[mt][3][r] * scale);
                lsum[mt][r] += (p0 + p1) + (p2 + p3);
                __bf16* pb = Pw + (mt * 16 + quad * 4 + r) * 72 + l16;
                pb[0]  = (__bf16)p0;
                pb[16] = (__bf16)p1;
                pb[32] = (__bf16)p2;
                pb[48] = (__bf16)p3;
            }
        }

#pragma unroll
        for (int ks2 = 0; ks2 < 2; ++ks2) {
            bf16x8 af[2];
#pragma unroll
            for (int mt = 0; mt < 2; ++mt)
                af[mt] = *(const bf16x8*)(Pw + (mt * 16 + l16) * 72 + ks2 * 32 + quad * 8);
#pragma unroll
            for (int nt = 0; nt < 8; ++nt) {
                bf16x8 bv = *(const bf16x8*)(Vl + (nt * 16 + l16) * 72 + ks2 * 32 + quad * 8);
#pragma unroll
                for (int mt = 0; mt < 2; ++mt)
                    o_acc[mt][nt] = __builtin_amdgcn_mfma_f32_16x16x32_bf16(af[mt], bv, o_acc[mt][nt], 0, 0, 0);
            }
        }
        __syncthreads();
    }

    const long pbase = (((long)(kc * NH + h) * NQB + qb)) * 128;
#pragma unroll
    for (int mt = 0; mt < 2; ++mt) {
#pragma unroll
        for (int r = 0; r < 4; ++r) {
            float ls = lsum[mt][r];
            ls += __shfl_xor(ls, 1);
            ls += __shfl_xor(ls, 2);
            ls += __shfl_xor(ls, 4);
            ls += __shfl_xor(ls, 8);
            const int row = w * 32 + mt * 16 + quad * 4 + r;
            if (l16 == 0) lsp[pbase + row] = ls;
            float* od = Osp + (pbase + row) * 128;
#pragma unroll
            for (int nt = 0; nt < 8; ++nt)
                od[nt * 16 + l16] = o_acc[mt][nt][r];
        }
    }
}

extern "C" void kernel_launch(void* const* d_in, const int* in_sizes, int n_in,
                              void* d_out, int out_size, void* d_ws, size_t ws_size,
                              hipStream_t stream)
{
    const float* q = (const float*)d_in[0];
    const float* k = (const float*)d_in[1];
    const float* v = (const float*)d_in[2];
    const float* w = (const float*)d_in[3];
    const float* b = (const float*)d_in[4];
    float* out = (float*)d_out;
    char* ws = (char*)d_ws;

    // workspace (~51.4 MB). kvp aliases Osp exactly (33,554,432 B each):
    // kvp dead after k_reduce_m; Osp written by k_sparse afterwards. Serial stream.
    __bf16* kb16 = (__bf16*)(ws + 0);          //  8,388,608  K bf16 [h][l][d]
    __bf16* vt16 = (__bf16*)(ws + 8388608);    //  8,388,608  V bf16 [h][d][l]
    float*  Osp  = (float*)(ws + 16777216);    // 33,554,432  sparse O partials [kc][h][qb][row][e]
    float*  kvp  = (float*)(ws + 16777216);    // 33,554,432  (alias) kv partials [h][ch][c][d]
    float*  lsp  = (float*)(ws + 50331648);    //    262,144  sparse l partials
    float*  pks  = (float*)(ws + 50593792);    //    262,144
    int*    lut  = (int*)  (ws + 50855936);    //     32,768
    float*  ksp  = (float*)(ws + 50888704);    //    262,144  ksum partials (64 chunks)
    float*  ksum = (float*)(ws + 51150848);    //      4,096
    __bf16* Mt   = (__bf16*)(ws + 51154944);   //    262,144  (kv @ W^T)^T bf16 [h][e][c]

    k_prep_kv <<<dim3(64, 8),   dim3(256), 0, stream>>>(k, v, kb16, vt16, pks);
    k_route   <<<dim3(32, 8),   dim3(256), 0, stream>>>(q, pks, lut);
    k_kvpart  <<<dim3(KVCH, 8), dim3(256), 0, stream>>>(k, v, kvp, ksp);
    k_reduce_m<<<dim3(32, 8),   dim3(128), 0, stream>>>(kvp, ksp, w, Mt, ksum);
    k_sparse  <<<dim3(512),     dim3(256), 0, stream>>>(q, kb16, vt16, lut, Osp, lsp);
    k_linear  <<<dim3(32, 8),   dim3(256), 0, stream>>>(q, Mt, ksum, b, Osp, lsp, out); // writes d_out
}